// Round 1
// baseline (467.779 us; speedup 1.0000x reference)
//
#include <hip/hip_runtime.h>

typedef unsigned short u16;
typedef unsigned int u32;
typedef __attribute__((ext_vector_type(8))) short bf16x8;
typedef __attribute__((ext_vector_type(4))) short bf16x4;
typedef __attribute__((ext_vector_type(4))) float f32x4;

#define MFMA(a, b, c) __builtin_amdgcn_mfma_f32_16x16x32_bf16(a, b, c, 0, 0, 0)
#define ASYNC16(g, l)                                                        \
  __builtin_amdgcn_global_load_lds(                                          \
      (const __attribute__((address_space(1))) u32*)(g),                     \
      (__attribute__((address_space(3))) u32*)(l), 16, 0, 0)

// compiler-level memory fence bracketing a raw s_barrier (prevents hoisting
// LDS reads / async stages across the barrier; emits no instructions)
#define SBARRIER()                                                           \
  do {                                                                       \
    asm volatile("" ::: "memory");                                           \
    __builtin_amdgcn_s_barrier();                                            \
    asm volatile("" ::: "memory");                                           \
  } while (0)

__device__ __forceinline__ float b2f(u16 u) {
  union { u32 i; float f; } x; x.i = ((u32)u) << 16; return x.f;
}
__device__ __forceinline__ u16 f2b(float f) {
  union { float f; u32 i; } x; x.f = f;
  return (u16)((x.i + 0x7fff + ((x.i >> 16) & 1)) >> 16);
}
__device__ __forceinline__ f32x4 fzero4() { f32x4 z = {0.f, 0.f, 0.f, 0.f}; return z; }

// ---------------------------------------------------------------------------
// x fp32 [4096*2048] -> bf16
// ---------------------------------------------------------------------------
__global__ __launch_bounds__(256) void cvt_x(const float* __restrict__ src,
                                             u16* __restrict__ dst) {
  const int i = (blockIdx.x * 256 + threadIdx.x) * 4;
  const f32x4 v = *(const f32x4*)(src + i);
  bf16x4 o;
  o[0] = (short)f2b(v[0]); o[1] = (short)f2b(v[1]);
  o[2] = (short)f2b(v[2]); o[3] = (short)f2b(v[3]);
  *(bf16x4*)(dst + i) = o;
}

// ---------------------------------------------------------------------------
// Weight transpose + cast (single): W fp32 [K][N] -> WT bf16 [N][K].
// ---------------------------------------------------------------------------
__global__ __launch_bounds__(256) void wtrans_f32(const float* __restrict__ src,
                                                  u16* __restrict__ dst) {
  __shared__ u16 tile[64][65];
  const int k0 = blockIdx.y * 64, n0 = blockIdx.x * 64;
  const int t = threadIdx.x;
  const int tr = t >> 3, tc = t & 7;

#pragma unroll
  for (int hh = 0; hh < 2; ++hh) {
    const int k = tr + hh * 32;
    const float* p = src + (size_t)(k0 + k) * 2048 + n0 + tc * 8;
    const f32x4 a = *(const f32x4*)(p);
    const f32x4 b = *(const f32x4*)(p + 4);
#pragma unroll
    for (int j = 0; j < 4; ++j) tile[k][tc * 8 + j] = f2b(a[j]);
#pragma unroll
    for (int j = 0; j < 4; ++j) tile[k][tc * 8 + 4 + j] = f2b(b[j]);
  }
  __syncthreads();
#pragma unroll
  for (int hh = 0; hh < 2; ++hh) {
    const int n = tr + hh * 32;
    bf16x8 v;
#pragma unroll
    for (int j = 0; j < 8; ++j) v[j] = (short)tile[tc * 8 + j][n];
    *(bf16x8*)(dst + (size_t)(n0 + n) * 2048 + k0 + tc * 8) = v;
  }
}

// z-indexed variant: z=0,1,2 -> wq,wk,wv into wTall + z*2048*2048.
__global__ __launch_bounds__(256) void wtrans3(const float* __restrict__ wq,
                                               const float* __restrict__ wk,
                                               const float* __restrict__ wv,
                                               u16* __restrict__ wTall) {
  __shared__ u16 tile[64][65];
  const int z = blockIdx.z;
  const float* src = (z == 0) ? wq : (z == 1) ? wk : wv;
  u16* dst = wTall + (size_t)z * 2048 * 2048;
  const int k0 = blockIdx.y * 64, n0 = blockIdx.x * 64;
  const int t = threadIdx.x;
  const int tr = t >> 3, tc = t & 7;

#pragma unroll
  for (int hh = 0; hh < 2; ++hh) {
    const int k = tr + hh * 32;
    const float* p = src + (size_t)(k0 + k) * 2048 + n0 + tc * 8;
    const f32x4 a = *(const f32x4*)(p);
    const f32x4 b = *(const f32x4*)(p + 4);
#pragma unroll
    for (int j = 0; j < 4; ++j) tile[k][tc * 8 + j] = f2b(a[j]);
#pragma unroll
    for (int j = 0; j < 4; ++j) tile[k][tc * 8 + 4 + j] = f2b(b[j]);
  }
  __syncthreads();
#pragma unroll
  for (int hh = 0; hh < 2; ++hh) {
    const int n = tr + hh * 32;
    bf16x8 v;
#pragma unroll
    for (int j = 0; j < 8; ++j) v[j] = (short)tile[tc * 8 + j][n];
    *(bf16x8*)(dst + (size_t)(n0 + n) * 2048 + k0 + tc * 8) = v;
  }
}

// ---------------------------------------------------------------------------
// Shared GEMM mainloop for gemm_out (m97 structure, unchanged).
// ---------------------------------------------------------------------------
__device__ __forceinline__ void gemm_mainloop(const u16* __restrict__ A,
                                              const u16* __restrict__ Bt,
                                              int K, int m0, int n0,
                                              u16* lA, u16* lB,
                                              f32x4 acc[4][4]) {
  const int tid = threadIdx.x;
  const int lane = tid & 63;
  const int wave = tid >> 6;
  const int quad = lane >> 4;
  const int l16 = lane & 15;
  const int wr = wave >> 1, wc = wave & 1;

  const int srow = lane >> 2;
  const int scol = (lane & 3) * 8;
  const u16* ga0 = A + (size_t)(m0 + (wave * 2 + 0) * 16 + srow) * K + scol;
  const u16* ga1 = A + (size_t)(m0 + (wave * 2 + 1) * 16 + srow) * K + scol;
  const u16* gb0 = Bt + (size_t)(n0 + (wave * 2 + 0) * 16 + srow) * K + scol;
  const u16* gb1 = Bt + (size_t)(n0 + (wave * 2 + 1) * 16 + srow) * K + scol;
  u16* la0 = lA + (wave * 2 + 0) * 512;
  u16* la1 = lA + (wave * 2 + 1) * 512;
  u16* lb0 = lB + (wave * 2 + 0) * 512;
  u16* lb1 = lB + (wave * 2 + 1) * 512;

  for (int k0 = 0; k0 < K; k0 += 32) {
    ASYNC16(ga0 + k0, la0);
    ASYNC16(ga1 + k0, la1);
    ASYNC16(gb0 + k0, lb0);
    ASYNC16(gb1 + k0, lb1);
    __syncthreads();
    bf16x8 af[4], bfr[4];
#pragma unroll
    for (int mb = 0; mb < 4; ++mb)
      af[mb] = *(const bf16x8*)(lA + ((wr * 64 + mb * 16 + l16) * 32 + quad * 8));
#pragma unroll
    for (int nb = 0; nb < 4; ++nb)
      bfr[nb] = *(const bf16x8*)(lB + ((wc * 64 + nb * 16 + l16) * 32 + quad * 8));
#pragma unroll
    for (int mb = 0; mb < 4; ++mb)
#pragma unroll
      for (int nb = 0; nb < 4; ++nb)
        acc[mb][nb] = MFMA(af[mb], bfr[nb], acc[mb][nb]);
    __syncthreads();
  }
}

// ---------------------------------------------------------------------------
// gemm_qkv2: 256x256 tile, BK=32, 8 waves (2x4), ring-4 LDS slots, counted
// vmcnt deep pipeline (T1+T2+T3+T4+T5 port of the 8-phase template).
//
// LDS slot layout (per operand, per slot, 16 KiB): quad-major
//   [kq 0..3][row 0..255][8 bf16]  -> fragment ds_read_b128 is conflict-free
// Staged with linear-dest global_load_lds: thread tid covers
//   (kq = tid>>8 (+2 for second load), row = tid&255), so the per-lane GLOBAL
//   address carries the permutation while the LDS dest stays linear.
// ---------------------------------------------------------------------------
__global__ __launch_bounds__(512, 2) void gemm_qkv2(const u16* __restrict__ A,
                                                    const u16* __restrict__ Bt,
                                                    u16* __restrict__ qkv) {
  __shared__ u16 lA[4 * 8192];  // 4 slots x 16 KiB
  __shared__ u16 lB[4 * 8192];

  // bijective XCD swizzle (384 blocks, 384 % 8 == 0)
  const int orig = blockIdx.x;
  const int wg = (orig & 7) * 48 + (orig >> 3);
  const int m0 = (wg / 24) * 256;
  const int n0 = (wg % 24) * 256;

  const int tid = threadIdx.x;
  const int lane = tid & 63;
  const int wave = tid >> 6;          // 0..7
  const int quad = lane >> 4, l16 = lane & 15;
  const int wr = wave >> 2, wc = wave & 3;  // 2 x 4 wave grid

  // staging: per-lane global source, wave-uniform LDS dest
  const int srow = tid & 255;
  const int sq = tid >> 8;  // 0..1 (loads j=0,1 add +0/+2 quads)
  const u16* gA = A + (size_t)(m0 + srow) * 2048 + sq * 8;
  const u16* gB = Bt + (size_t)(n0 + srow) * 2048 + sq * 8;
  const int ldst = wave * 512;  // u16 offset; HW adds lane*16B

#define STAGE_A(t)                                                           \
  do {                                                                       \
    u16* d_ = lA + (((t) & 3) << 13) + ldst;                                 \
    ASYNC16(gA + (t) * 32, d_);                                              \
    ASYNC16(gA + (t) * 32 + 16, d_ + 4096);                                  \
  } while (0)
#define STAGE_B(t)                                                           \
  do {                                                                       \
    u16* d_ = lB + (((t) & 3) << 13) + ldst;                                 \
    ASYNC16(gB + (t) * 32, d_);                                              \
    ASYNC16(gB + (t) * 32 + 16, d_ + 4096);                                  \
  } while (0)

  f32x4 acc[8][4];
#pragma unroll
  for (int i = 0; i < 8; ++i)
#pragma unroll
    for (int j = 0; j < 4; ++j) acc[i][j] = fzero4();

  // prologue: stage tiles 0,1,2 (12 loads/thread), wait tile 0 (keep 8 in flight)
  STAGE_A(0); STAGE_B(0);
  STAGE_A(1); STAGE_B(1);
  STAGE_A(2); STAGE_B(2);
  asm volatile("s_waitcnt vmcnt(8)" ::: "memory");
  SBARRIER();

  const int aoff = wr * 128 + l16;  // + mb*16
  const int boff = wc * 64 + l16;   // + nb*16

  for (int t = 0; t < 64; ++t) {
    const u16* sA = lA + ((t & 3) << 13) + quad * 2048;
    const u16* sB = lB + ((t & 3) << 13) + quad * 2048;

    // ---------------- phase A: mb 0..3 x nb 0..3 ----------------
    bf16x8 af[4], bfr[4];
#pragma unroll
    for (int mb = 0; mb < 4; ++mb)
      af[mb] = *(const bf16x8*)(sA + (aoff + mb * 16) * 8);
#pragma unroll
    for (int nb = 0; nb < 4; ++nb)
      bfr[nb] = *(const bf16x8*)(sB + (boff + nb * 16) * 8);
    if (t <= 60) STAGE_A(t + 3);
    SBARRIER();
    asm volatile("s_waitcnt lgkmcnt(0)" ::: "memory");
    __builtin_amdgcn_s_setprio(1);
#pragma unroll
    for (int mb = 0; mb < 4; ++mb)
#pragma unroll
      for (int nb = 0; nb < 4; ++nb)
        acc[mb][nb] = MFMA(af[mb], bfr[nb], acc[mb][nb]);
    __builtin_amdgcn_s_setprio(0);
    SBARRIER();

    // ---------------- phase B: mb 4..7 x nb 0..3 ----------------
#pragma unroll
    for (int mb = 0; mb < 4; ++mb)
      af[mb] = *(const bf16x8*)(sA + (aoff + (mb + 4) * 16) * 8);
    if (t <= 60) STAGE_B(t + 3);
    SBARRIER();
    asm volatile("s_waitcnt lgkmcnt(0)" ::: "memory");
    __builtin_amdgcn_s_setprio(1);
#pragma unroll
    for (int mb = 0; mb < 4; ++mb)
#pragma unroll
      for (int nb = 0; nb < 4; ++nb)
        acc[mb + 4][nb] = MFMA(af[mb], bfr[nb], acc[mb + 4][nb]);
    __builtin_amdgcn_s_setprio(0);
    // tile-boundary wait: guarantee tile t+1 resident; keep t+2/t+3 in flight
    if (t < 61) {
      asm volatile("s_waitcnt vmcnt(8)" ::: "memory");
    } else if (t == 61) {
      asm volatile("s_waitcnt vmcnt(4)" ::: "memory");
    } else if (t == 62) {
      asm volatile("s_waitcnt vmcnt(0)" ::: "memory");
    }
    SBARRIER();
  }
#undef STAGE_A
#undef STAGE_B

  // epilogue: scatter to Q/K/V layout [which][b*16+h][s][d]
  const size_t BUF = (size_t)4096 * 2048;
#pragma unroll
  for (int mb = 0; mb < 8; ++mb)
#pragma unroll
    for (int nb = 0; nb < 4; ++nb)
#pragma unroll
      for (int r = 0; r < 4; ++r) {
        const int row = m0 + wr * 128 + mb * 16 + quad * 4 + r;  // 0..4095
        const int col = n0 + wc * 64 + nb * 16 + l16;            // 0..6143
        const int b = row >> 11, s = row & 2047;
        const int which = col >> 11, rem = col & 2047;
        const int hh = rem >> 7, d = rem & 127;
        const size_t idx = (size_t)which * BUF +
                           (((size_t)(b * 16 + hh) * 2048 + s) * 128 + d);
        qkv[idx] = f2b(acc[mb][nb][r]);
      }
}

// O[4096,2048] @ woT^T -> out fp32 [4096,2048]
__global__ __launch_bounds__(256) void gemm_out(const u16* __restrict__ Oin,
                                                const u16* __restrict__ woT,
                                                float* __restrict__ out) {
  __shared__ u16 lA[128 * 32];
  __shared__ u16 lB[128 * 32];
  f32x4 acc[4][4];
#pragma unroll
  for (int i = 0; i < 4; ++i)
#pragma unroll
    for (int j = 0; j < 4; ++j) acc[i][j] = fzero4();

  const int m0 = blockIdx.y * 128, n0 = blockIdx.x * 128;
  gemm_mainloop(Oin, woT, 2048, m0, n0, lA, lB, acc);

  const int lane = threadIdx.x & 63, wave = threadIdx.x >> 6;
  const int quad = lane >> 4, l16 = lane & 15;
  const int wr = wave >> 1, wc = wave & 1;
#pragma unroll
  for (int mb = 0; mb < 4; ++mb)
#pragma unroll
    for (int nb = 0; nb < 4; ++nb)
#pragma unroll
      for (int r = 0; r < 4; ++r) {
        const int row = m0 + wr * 64 + mb * 16 + quad * 4 + r;
        const int col = n0 + wc * 64 + nb * 16 + l16;
        out[(size_t)row * 2048 + col] = acc[mb][nb][r];
      }
}

// ---------------------------------------------------------------------------
// RoPE in place on Q and K; folds 1/sqrt(128) into Q.
// ---------------------------------------------------------------------------
__global__ __launch_bounds__(256) void rope_kernel(u16* __restrict__ Q,
                                                   u16* __restrict__ K,
                                                   const float* __restrict__ fcos,
                                                   const float* __restrict__ fsin) {
  const int i = blockIdx.x * 256 + threadIdx.x;
  const int d = i & 63;
  const int s = (i >> 6) & 2047;
  const int bh = i >> 17;
  const size_t base = ((size_t)bh * 2048 + s) * 128;
  const float c = fcos[s * 64 + d];
  const float sn = fsin[s * 64 + d];
  const float qs = 0.08838834764831845f;

  const float q0 = b2f(Q[base + d]), q1 = b2f(Q[base + d + 64]);
  Q[base + d] = f2b((q0 * c - q1 * sn) * qs);
  Q[base + d + 64] = f2b((q1 * c + q0 * sn) * qs);
  const float k0 = b2f(K[base + d]), k1 = b2f(K[base + d + 64]);
  K[base + d] = f2b(k0 * c - k1 * sn);
  K[base + d + 64] = f2b(k1 * c + k0 * sn);
}

// ---------------------------------------------------------------------------
// Flash attention v2.  BM=64 (16 rows/wave), BN=64.  (unchanged this round)
// ---------------------------------------------------------------------------
__global__ __launch_bounds__(256) void attn2(const u16* __restrict__ Q,
                                             const u16* __restrict__ K,
                                             const u16* __restrict__ V,
                                             u16* __restrict__ O) {
  __shared__ u16 lK[64 * 136];       // K-tile [n][k], padded
  __shared__ u16 lV[128 * 72];       // V-tile transposed [d][n], padded
  __shared__ u16 lP[4 * 16 * 72];    // per-wave P, padded

  const int bh = blockIdx.y;
  const int b = bh >> 4, h = bh & 15;
  const u16* Qh = Q + (size_t)bh * 2048 * 128;
  const u16* Kh = K + (size_t)bh * 2048 * 128;
  const u16* Vh = V + (size_t)bh * 2048 * 128;

  const int tid = threadIdx.x;
  const int lane = tid & 63, wave = tid >> 6;
  const int quad = lane >> 4, l16 = lane & 15;
  const int np = tid & 31, dg = tid >> 5;
  const int d0 = dg * 16, r0 = np * 2;
  const int krow = tid >> 4, kj = tid & 15;
  u16* lPw = lP + wave * (16 * 72);

  bf16x8 kreg[4], vreg[4];

#pragma unroll
  for (int half = 0; half < 2; ++half) {
    const int qt = (half == 0) ? (int)blockIdx.x : 31 - (int)blockIdx.x;
    const int q0 = qt * 64;

    bf16x8 qf[4];
    {
      const u16* qrow = Qh + (size_t)(q0 + wave * 16 + l16) * 128 + quad * 8;
#pragma unroll
      for (int kc = 0; kc < 4; ++kc) qf[kc] = *(const bf16x8*)(qrow + kc * 32);
    }

    float m_i[4], l_i[4];
    f32x4 accO[8];
#pragma unroll
    for (int r = 0; r < 4; ++r) { m_i[r] = -1e30f; l_i[r] = 0.f; }
#pragma unroll
    for (int db = 0; db < 8; ++db) accO[db] = fzero4();

    {
#pragma unroll
      for (int i = 0; i < 4; ++i)
        kreg[i] = *(const bf16x8*)(Kh + (size_t)(krow + 16 * i) * 128 + kj * 8);
      const u16* vp = Vh + (size_t)r0 * 128 + d0;
      vreg[0] = *(const bf16x8*)(vp);
      vreg[1] = *(const bf16x8*)(vp + 8);
      vreg[2] = *(const bf16x8*)(vp + 128);
      vreg[3] = *(const bf16x8*)(vp + 136);
    }

    for (int n0 = 0; n0 <= q0; n0 += 64) {
#pragma unroll
      for (int i = 0; i < 4; ++i)
        *(bf16x8*)(lK + (krow + 16 * i) * 136 + kj * 8) = kreg[i];
#pragma unroll
      for (int j = 0; j < 8; ++j) {
        const u32 lo = (u16)vreg[0][j], hi = (u16)vreg[2][j];
        *(u32*)(lV + (d0 + j) * 72 + r0) = lo | (hi << 16);
      }
#pragma unroll
      for (int j = 0; j < 8; ++j) {
        const u32 lo = (u16)vreg[1][j], hi = (u16)vreg[3][j];
        *(u32*)(lV + (d0 + 8 + j) * 72 + r0) = lo | (hi << 16);
      }
      __syncthreads();

      if (n0 + 64 <= q0) {
        const int nn = n0 + 64;
#pragma unroll
        for (int i = 0; i < 4; ++i)
          kreg[i] = *(const bf16x8*)(Kh + (size_t)(nn + krow + 16 * i) * 128 + kj * 8);
        const u16* vp = Vh + (size_t)(nn + r0) * 128 + d0;
        vreg[0] = *(const bf16x8*)(vp);
        vreg[1] = *(const bf16x8*)(vp + 8);
        vreg[2] = *(const bf16x8*)(vp + 128);
        vreg[3] = *(const bf16x8*)(vp + 136);
      }

      f32x4 sf[4];
#pragma unroll
      for (int nb = 0; nb < 4; ++nb) {
        sf[nb] = fzero4();
#pragma unroll
        for (int kc = 0; kc < 4; ++kc) {
          bf16x8 kf = *(const bf16x8*)(lK + ((nb * 16 + l16) * 136 + kc * 32 + quad * 8));
          sf[nb] = MFMA(qf[kc], kf, sf[nb]);
        }
      }
      if (n0 == q0) {
#pragma unroll
        for (int nb = 0; nb < 4; ++nb)
#pragma unroll
          for (int r = 0; r < 4; ++r) {
            const int rowl = wave * 16 + quad * 4 + r;
            const int coll = nb * 16 + l16;
            if (coll > rowl) sf[nb][r] = -1e30f;
          }
      }
      float pr[4][4], alpha[4];
#pragma unroll
      for (int r = 0; r < 4; ++r) {
        float mx = fmaxf(fmaxf(sf[0][r], sf[1][r]), fmaxf(sf[2][r], sf[3][r]));
#pragma unroll
        for (int off = 1; off < 16; off <<= 1) mx = fmaxf(mx, __shfl_xor(mx, off));
        const float mn = fmaxf(m_i[r], mx);
        alpha[r] = __expf(m_i[r] - mn);
        m_i[r] = mn;
        float rs = 0.f;
#pragma unroll
        for (int nb = 0; nb < 4; ++nb) {
          const float p = __expf(sf[nb][r] - mn);
          pr[nb][r] = p;
          rs += p;
        }
#pragma unroll
        for (int off = 1; off < 16; off <<= 1) rs += __shfl_xor(rs, off);
        l_i[r] = l_i[r] * alpha[r] + rs;
      }
#pragma unroll
      for (int db = 0; db < 8; ++db)
#pragma unroll
        for (int r = 0; r < 4; ++r) accO[db][r] *= alpha[r];

#pragma unroll
      for (int nb = 0; nb < 4; ++nb)
#pragma unroll
        for (int r = 0; r < 4; ++r)
          lPw[(quad * 4 + r) * 72 + nb * 16 + l16] = f2b(pr[nb][r]);
      __syncthreads();

#pragma unroll
      for (int kc2 = 0; kc2 < 2; ++kc2) {
        bf16x8 pf = *(const bf16x8*)(lPw + (l16 * 72 + kc2 * 32 + quad * 8));
#pragma unroll
        for (int db = 0; db < 8; ++db) {
          bf16x8 vf = *(const bf16x8*)(lV + ((db * 16 + l16) * 72 + kc2 * 32 + quad * 8));
          accO[db] = MFMA(pf, vf, accO[db]);
        }
      }
      __syncthreads();
    }

#pragma unroll
    for (int r = 0; r < 4; ++r) {
      const float inv = 1.0f / l_i[r];
      const int srow = q0 + wave * 16 + quad * 4 + r;
      u16* orow = O + ((size_t)b * 2048 + srow) * 2048 + h * 128;
#pragma unroll
      for (int db = 0; db < 8; ++db)
        orow[db * 16 + l16] = f2b(accO[db][r] * inv);
    }
  }
}

// ---------------------------------------------------------------------------
// Workspace (64 MiB): B0 = xb -> Ob alias, B1=Qb, B2=Kb, B3=Vb.
// wq/wk/wv transposed (25.2 MB) live in d_out (33.5 MB fp32, overwritten by
// gemm_out at the end); woT in Kb (dead after attn).
// ---------------------------------------------------------------------------
extern "C" void kernel_launch(void* const* d_in, const int* in_sizes, int n_in,
                              void* d_out, int out_size, void* d_ws, size_t ws_size,
                              hipStream_t stream) {
  const float* x  = (const float*)d_in[0];
  const float* fc = (const float*)d_in[1];
  const float* fs = (const float*)d_in[2];
  const float* wq = (const float*)d_in[3];
  const float* wk = (const float*)d_in[4];
  const float* wv = (const float*)d_in[5];
  const float* wo = (const float*)d_in[6];
  float* out = (float*)d_out;

  u16* ws = (u16*)d_ws;
  const size_t BUF = (size_t)4096 * 2048;
  u16* xb  = ws;
  u16* Ob  = ws;            // reuse B0 (xb dead after gemm_qkv)
  u16* Qb  = ws + 1 * BUF;
  u16* Kb  = ws + 2 * BUF;
  u16* Vb  = ws + 3 * BUF;
  u16* wTall = (u16*)d_out; // 6144*2048 bf16 = 25.2 MB scratch in d_out
  u16* woT = Kb;            // wo transpose (Kb dead after attn)

  hipLaunchKernelGGL(cvt_x, dim3(8192), dim3(256), 0, stream, x, xb);
  hipLaunchKernelGGL(wtrans3, dim3(32, 32, 3), dim3(256), 0, stream, wq, wk, wv, wTall);
  hipLaunchKernelGGL(gemm_qkv2, dim3(384), dim3(512), 0, stream, xb, wTall, Qb);
  hipLaunchKernelGGL(rope_kernel, dim3(16384), dim3(256), 0, stream, Qb, Kb, fc, fs);
  hipLaunchKernelGGL(attn2, dim3(16, 32), dim3(256), 0, stream, Qb, Kb, Vb, Ob);
  hipLaunchKernelGGL(wtrans_f32, dim3(32, 32), dim3(256), 0, stream, wo, woT);
  hipLaunchKernelGGL(gemm_out, dim3(16, 32), dim3(256), 0, stream, Ob, woT, out);
}

// Round 2
// 418.863 us; speedup vs baseline: 1.1168x; 1.1168x over previous
//
#include <hip/hip_runtime.h>

typedef unsigned short u16;
typedef unsigned int u32;
typedef __attribute__((ext_vector_type(8))) short bf16x8;
typedef __attribute__((ext_vector_type(4))) short bf16x4;
typedef __attribute__((ext_vector_type(4))) float f32x4;

#define MFMA(a, b, c) __builtin_amdgcn_mfma_f32_16x16x32_bf16(a, b, c, 0, 0, 0)
#define ASYNC16(g, l)                                                        \
  __builtin_amdgcn_global_load_lds(                                          \
      (const __attribute__((address_space(1))) u32*)(g),                     \
      (__attribute__((address_space(3))) u32*)(l), 16, 0, 0)

__device__ __forceinline__ float b2f(u16 u) {
  union { u32 i; float f; } x; x.i = ((u32)u) << 16; return x.f;
}
__device__ __forceinline__ u16 f2b(float f) {
  union { float f; u32 i; } x; x.f = f;
  return (u16)((x.i + 0x7fff + ((x.i >> 16) & 1)) >> 16);
}
__device__ __forceinline__ f32x4 fzero4() { f32x4 z = {0.f, 0.f, 0.f, 0.f}; return z; }

// ---------------------------------------------------------------------------
// x fp32 [4096*2048] -> bf16
// ---------------------------------------------------------------------------
__global__ __launch_bounds__(256) void cvt_x(const float* __restrict__ src,
                                             u16* __restrict__ dst) {
  const int i = (blockIdx.x * 256 + threadIdx.x) * 4;
  const f32x4 v = *(const f32x4*)(src + i);
  bf16x4 o;
  o[0] = (short)f2b(v[0]); o[1] = (short)f2b(v[1]);
  o[2] = (short)f2b(v[2]); o[3] = (short)f2b(v[3]);
  *(bf16x4*)(dst + i) = o;
}

// ---------------------------------------------------------------------------
// Weight transpose + cast (single): W fp32 [K][N] -> WT bf16 [N][K].
// ---------------------------------------------------------------------------
__global__ __launch_bounds__(256) void wtrans_f32(const float* __restrict__ src,
                                                  u16* __restrict__ dst) {
  __shared__ u16 tile[64][65];
  const int k0 = blockIdx.y * 64, n0 = blockIdx.x * 64;
  const int t = threadIdx.x;
  const int tr = t >> 3, tc = t & 7;

#pragma unroll
  for (int hh = 0; hh < 2; ++hh) {
    const int k = tr + hh * 32;
    const float* p = src + (size_t)(k0 + k) * 2048 + n0 + tc * 8;
    const f32x4 a = *(const f32x4*)(p);
    const f32x4 b = *(const f32x4*)(p + 4);
#pragma unroll
    for (int j = 0; j < 4; ++j) tile[k][tc * 8 + j] = f2b(a[j]);
#pragma unroll
    for (int j = 0; j < 4; ++j) tile[k][tc * 8 + 4 + j] = f2b(b[j]);
  }
  __syncthreads();
#pragma unroll
  for (int hh = 0; hh < 2; ++hh) {
    const int n = tr + hh * 32;
    bf16x8 v;
#pragma unroll
    for (int j = 0; j < 8; ++j) v[j] = (short)tile[tc * 8 + j][n];
    *(bf16x8*)(dst + (size_t)(n0 + n) * 2048 + k0 + tc * 8) = v;
  }
}

// z-indexed variant: z=0,1,2 -> wq,wk,wv into wTall + z*2048*2048.
__global__ __launch_bounds__(256) void wtrans3(const float* __restrict__ wq,
                                               const float* __restrict__ wk,
                                               const float* __restrict__ wv,
                                               u16* __restrict__ wTall) {
  __shared__ u16 tile[64][65];
  const int z = blockIdx.z;
  const float* src = (z == 0) ? wq : (z == 1) ? wk : wv;
  u16* dst = wTall + (size_t)z * 2048 * 2048;
  const int k0 = blockIdx.y * 64, n0 = blockIdx.x * 64;
  const int t = threadIdx.x;
  const int tr = t >> 3, tc = t & 7;

#pragma unroll
  for (int hh = 0; hh < 2; ++hh) {
    const int k = tr + hh * 32;
    const float* p = src + (size_t)(k0 + k) * 2048 + n0 + tc * 8;
    const f32x4 a = *(const f32x4*)(p);
    const f32x4 b = *(const f32x4*)(p + 4);
#pragma unroll
    for (int j = 0; j < 4; ++j) tile[k][tc * 8 + j] = f2b(a[j]);
#pragma unroll
    for (int j = 0; j < 4; ++j) tile[k][tc * 8 + 4 + j] = f2b(b[j]);
  }
  __syncthreads();
#pragma unroll
  for (int hh = 0; hh < 2; ++hh) {
    const int n = tr + hh * 32;
    bf16x8 v;
#pragma unroll
    for (int j = 0; j < 8; ++j) v[j] = (short)tile[tc * 8 + j][n];
    *(bf16x8*)(dst + (size_t)(n0 + n) * 2048 + k0 + tc * 8) = v;
  }
}

// ---------------------------------------------------------------------------
// Shared GEMM mainloop (m97 structure — proven 127 us / 811 TF on qkv).
// ---------------------------------------------------------------------------
__device__ __forceinline__ void gemm_mainloop(const u16* __restrict__ A,
                                              const u16* __restrict__ Bt,
                                              int K, int m0, int n0,
                                              u16* lA, u16* lB,
                                              f32x4 acc[4][4]) {
  const int tid = threadIdx.x;
  const int lane = tid & 63;
  const int wave = tid >> 6;
  const int quad = lane >> 4;
  const int l16 = lane & 15;
  const int wr = wave >> 1, wc = wave & 1;

  const int srow = lane >> 2;
  const int scol = (lane & 3) * 8;
  const u16* ga0 = A + (size_t)(m0 + (wave * 2 + 0) * 16 + srow) * K + scol;
  const u16* ga1 = A + (size_t)(m0 + (wave * 2 + 1) * 16 + srow) * K + scol;
  const u16* gb0 = Bt + (size_t)(n0 + (wave * 2 + 0) * 16 + srow) * K + scol;
  const u16* gb1 = Bt + (size_t)(n0 + (wave * 2 + 1) * 16 + srow) * K + scol;
  u16* la0 = lA + (wave * 2 + 0) * 512;
  u16* la1 = lA + (wave * 2 + 1) * 512;
  u16* lb0 = lB + (wave * 2 + 0) * 512;
  u16* lb1 = lB + (wave * 2 + 1) * 512;

  for (int k0 = 0; k0 < K; k0 += 32) {
    ASYNC16(ga0 + k0, la0);
    ASYNC16(ga1 + k0, la1);
    ASYNC16(gb0 + k0, lb0);
    ASYNC16(gb1 + k0, lb1);
    __syncthreads();
    bf16x8 af[4], bfr[4];
#pragma unroll
    for (int mb = 0; mb < 4; ++mb)
      af[mb] = *(const bf16x8*)(lA + ((wr * 64 + mb * 16 + l16) * 32 + quad * 8));
#pragma unroll
    for (int nb = 0; nb < 4; ++nb)
      bfr[nb] = *(const bf16x8*)(lB + ((wc * 64 + nb * 16 + l16) * 32 + quad * 8));
#pragma unroll
    for (int mb = 0; mb < 4; ++mb)
#pragma unroll
      for (int nb = 0; nb < 4; ++nb)
        acc[mb][nb] = MFMA(af[mb], bfr[nb], acc[mb][nb]);
    __syncthreads();
  }
}

// x[4096,2048] @ wTall[6144,2048]^T -> Q/K/V (consecutive BUF-sized buffers).
__global__ __launch_bounds__(256) void gemm_qkv(const u16* __restrict__ x,
                                                const u16* __restrict__ wT,
                                                u16* __restrict__ qkv) {
  __shared__ u16 lA[128 * 32];
  __shared__ u16 lB[128 * 32];
  f32x4 acc[4][4];
#pragma unroll
  for (int i = 0; i < 4; ++i)
#pragma unroll
    for (int j = 0; j < 4; ++j) acc[i][j] = fzero4();

  const int m0 = blockIdx.y * 128, n0 = blockIdx.x * 128;
  gemm_mainloop(x, wT, 2048, m0, n0, lA, lB, acc);

  const int lane = threadIdx.x & 63, wave = threadIdx.x >> 6;
  const int quad = lane >> 4, l16 = lane & 15;
  const int wr = wave >> 1, wc = wave & 1;
#pragma unroll
  for (int mb = 0; mb < 4; ++mb)
#pragma unroll
    for (int nb = 0; nb < 4; ++nb)
#pragma unroll
      for (int r = 0; r < 4; ++r) {
        const int row = m0 + wr * 64 + mb * 16 + quad * 4 + r;  // 0..4095
        const int col = n0 + wc * 64 + nb * 16 + l16;           // 0..6143
        const int b = row >> 11, s = row & 2047;
        const int which = col >> 11, rem = col & 2047;
        const int hh = rem >> 7, d = rem & 127;
        const size_t idx = (size_t)which * ((size_t)4096 * 2048) +
                           (((size_t)(b * 16 + hh) * 2048 + s) * 128 + d);
        qkv[idx] = f2b(acc[mb][nb][r]);
      }
}

// O[4096,2048] @ woT^T -> out fp32 [4096,2048]
__global__ __launch_bounds__(256) void gemm_out(const u16* __restrict__ Oin,
                                                const u16* __restrict__ woT,
                                                float* __restrict__ out) {
  __shared__ u16 lA[128 * 32];
  __shared__ u16 lB[128 * 32];
  f32x4 acc[4][4];
#pragma unroll
  for (int i = 0; i < 4; ++i)
#pragma unroll
    for (int j = 0; j < 4; ++j) acc[i][j] = fzero4();

  const int m0 = blockIdx.y * 128, n0 = blockIdx.x * 128;
  gemm_mainloop(Oin, woT, 2048, m0, n0, lA, lB, acc);

  const int lane = threadIdx.x & 63, wave = threadIdx.x >> 6;
  const int quad = lane >> 4, l16 = lane & 15;
  const int wr = wave >> 1, wc = wave & 1;
#pragma unroll
  for (int mb = 0; mb < 4; ++mb)
#pragma unroll
    for (int nb = 0; nb < 4; ++nb)
#pragma unroll
      for (int r = 0; r < 4; ++r) {
        const int row = m0 + wr * 64 + mb * 16 + quad * 4 + r;
        const int col = n0 + wc * 64 + nb * 16 + l16;
        out[(size_t)row * 2048 + col] = acc[mb][nb][r];
      }
}

// ---------------------------------------------------------------------------
// RoPE in place on Q and K; folds 1/sqrt(128) into Q.
// ---------------------------------------------------------------------------
__global__ __launch_bounds__(256) void rope_kernel(u16* __restrict__ Q,
                                                   u16* __restrict__ K,
                                                   const float* __restrict__ fcos,
                                                   const float* __restrict__ fsin) {
  const int i = blockIdx.x * 256 + threadIdx.x;
  const int d = i & 63;
  const int s = (i >> 6) & 2047;
  const int bh = i >> 17;
  const size_t base = ((size_t)bh * 2048 + s) * 128;
  const float c = fcos[s * 64 + d];
  const float sn = fsin[s * 64 + d];
  const float qs = 0.08838834764831845f;

  const float q0 = b2f(Q[base + d]), q1 = b2f(Q[base + d + 64]);
  Q[base + d] = f2b((q0 * c - q1 * sn) * qs);
  Q[base + d + 64] = f2b((q1 * c + q0 * sn) * qs);
  const float k0 = b2f(K[base + d]), k1 = b2f(K[base + d + 64]);
  K[base + d] = f2b(k0 * c - k1 * sn);
  K[base + d + 64] = f2b(k1 * c + k0 * sn);
}

// ---------------------------------------------------------------------------
// Flash attention v3.  BM=64 (16 rows/wave, 4 waves), BN=128 KV tiles.
// vs v2: 17 iterations instead of 33 (halved barrier/softmax-shuffle/rescale
// counts), 2 barriers/iter instead of 3 (middle barrier removed: lP is
// per-wave private, double-pumped through the 16x72 buffer; same-wave DS ops
// are in-order), LDS 76 KiB -> 2 blocks/CU, grid 512 = exactly 2x256 CUs.
// ---------------------------------------------------------------------------
__global__ __launch_bounds__(256, 2) void attn3(const u16* __restrict__ Q,
                                                const u16* __restrict__ K,
                                                const u16* __restrict__ V,
                                                u16* __restrict__ O) {
  __shared__ u16 lK[128 * 136];      // K-tile [n][k], padded (2-way reads, free)
  __shared__ u16 lV[128 * 132];      // V-tile transposed [d][n], padded
  __shared__ u16 lP[4 * 16 * 72];    // per-wave P half-buffer (64 cols), padded

  const int bh = blockIdx.y;
  const int b = bh >> 4, h = bh & 15;
  const u16* Qh = Q + (size_t)bh * 2048 * 128;
  const u16* Kh = K + (size_t)bh * 2048 * 128;
  const u16* Vh = V + (size_t)bh * 2048 * 128;

  const int tid = threadIdx.x;
  const int lane = tid & 63, wave = tid >> 6;
  const int quad = lane >> 4, l16 = lane & 15;
  // K staging: rows krow+16i (i<8), 16B chunk kj
  const int krow = tid >> 4, kj = tid & 15;
  // V staging: rows r0, r0+1 (n), d-chunk d0..d0+31
  const int r0 = (tid & 63) * 2, d0 = (tid >> 6) * 32;
  u16* lPw = lP + wave * (16 * 72);

  bf16x8 kreg[8], vreg[8];

#pragma unroll
  for (int half = 0; half < 2; ++half) {
    const int qt = (half == 0) ? (int)blockIdx.x : 31 - (int)blockIdx.x;
    const int q0 = qt * 64;

    // Q fragments (registers, whole pass)
    bf16x8 qf[4];
    {
      const u16* qrow = Qh + (size_t)(q0 + wave * 16 + l16) * 128 + quad * 8;
#pragma unroll
      for (int kc = 0; kc < 4; ++kc) qf[kc] = *(const bf16x8*)(qrow + kc * 32);
    }

    float m_i[4], l_i[4];
    f32x4 accO[8];
#pragma unroll
    for (int r = 0; r < 4; ++r) { m_i[r] = -1e30f; l_i[r] = 0.f; }
#pragma unroll
    for (int db = 0; db < 8; ++db) accO[db] = fzero4();

    // prefetch first KV tile (n0 = 0)
    {
#pragma unroll
      for (int i = 0; i < 8; ++i)
        kreg[i] = *(const bf16x8*)(Kh + (size_t)(krow + 16 * i) * 128 + kj * 8);
      const u16* vp = Vh + (size_t)r0 * 128 + d0;
#pragma unroll
      for (int c = 0; c < 4; ++c) {
        vreg[c] = *(const bf16x8*)(vp + c * 8);
        vreg[4 + c] = *(const bf16x8*)(vp + 128 + c * 8);
      }
    }

    for (int n0 = 0; n0 <= q0; n0 += 128) {
      // ---- write staged regs to LDS
#pragma unroll
      for (int i = 0; i < 8; ++i)
        *(bf16x8*)(lK + (krow + 16 * i) * 136 + kj * 8) = kreg[i];
#pragma unroll
      for (int c = 0; c < 4; ++c)
#pragma unroll
        for (int j = 0; j < 8; ++j) {
          const u32 lo = (u16)vreg[c][j], hi = (u16)vreg[4 + c][j];
          *(u32*)(lV + (d0 + c * 8 + j) * 132 + r0) = lo | (hi << 16);
        }
      __syncthreads();

      // ---- prefetch next tile (overlaps compute)
      if (n0 + 128 <= q0) {
        const int nn = n0 + 128;
#pragma unroll
        for (int i = 0; i < 8; ++i)
          kreg[i] = *(const bf16x8*)(Kh + (size_t)(nn + krow + 16 * i) * 128 + kj * 8);
        const u16* vp = Vh + (size_t)(nn + r0) * 128 + d0;
#pragma unroll
        for (int c = 0; c < 4; ++c) {
          vreg[c] = *(const bf16x8*)(vp + c * 8);
          vreg[4 + c] = *(const bf16x8*)(vp + 128 + c * 8);
        }
      }

      // ---- S = Q K^T  (skip column groups that are fully masked)
      f32x4 sf[8];
      const int nbLim = (q0 + 64 - n0) >> 4;  // >=8 except on diagonal tiles
#pragma unroll
      for (int nb = 0; nb < 8; ++nb) {
        if (nb < nbLim) {
          sf[nb] = fzero4();
#pragma unroll
          for (int kc = 0; kc < 4; ++kc) {
            bf16x8 kf = *(const bf16x8*)(lK + ((nb * 16 + l16) * 136 + kc * 32 + quad * 8));
            sf[nb] = MFMA(qf[kc], kf, sf[nb]);
          }
        } else {
          sf[nb][0] = -1e30f; sf[nb][1] = -1e30f;
          sf[nb][2] = -1e30f; sf[nb][3] = -1e30f;
        }
      }
      if (n0 + 128 > q0) {  // diagonal tile: elementwise causal mask
#pragma unroll
        for (int nb = 0; nb < 8; ++nb)
#pragma unroll
          for (int r = 0; r < 4; ++r) {
            const int rowg = q0 + wave * 16 + quad * 4 + r;
            const int colg = n0 + nb * 16 + l16;
            if (colg > rowg) sf[nb][r] = -1e30f;
          }
      }

      // ---- online softmax (p values overwrite sf)
      float alpha[4];
#pragma unroll
      for (int r = 0; r < 4; ++r) {
        float mx = sf[0][r];
#pragma unroll
        for (int nb = 1; nb < 8; ++nb) mx = fmaxf(mx, sf[nb][r]);
#pragma unroll
        for (int off = 1; off < 16; off <<= 1) mx = fmaxf(mx, __shfl_xor(mx, off));
        const float mn = fmaxf(m_i[r], mx);
        alpha[r] = __expf(m_i[r] - mn);
        m_i[r] = mn;
        float rs = 0.f;
#pragma unroll
        for (int nb = 0; nb < 8; ++nb) {
          const float p = __expf(sf[nb][r] - mn);
          sf[nb][r] = p;
          rs += p;
        }
#pragma unroll
        for (int off = 1; off < 16; off <<= 1) rs += __shfl_xor(rs, off);
        l_i[r] = l_i[r] * alpha[r] + rs;
      }
#pragma unroll
      for (int db = 0; db < 8; ++db)
#pragma unroll
        for (int r = 0; r < 4; ++r) accO[db][r] *= alpha[r];

      // ---- P -> lPw (per-wave private; no barrier needed), double-pumped
      bf16x8 pf[4];
#pragma unroll
      for (int nb = 0; nb < 4; ++nb)
#pragma unroll
        for (int r = 0; r < 4; ++r)
          lPw[(quad * 4 + r) * 72 + nb * 16 + l16] = f2b(sf[nb][r]);
      pf[0] = *(const bf16x8*)(lPw + (l16 * 72 + quad * 8));
      pf[1] = *(const bf16x8*)(lPw + (l16 * 72 + 32 + quad * 8));
#pragma unroll
      for (int nb = 0; nb < 4; ++nb)
#pragma unroll
        for (int r = 0; r < 4; ++r)
          lPw[(quad * 4 + r) * 72 + nb * 16 + l16] = f2b(sf[nb + 4][r]);
      pf[2] = *(const bf16x8*)(lPw + (l16 * 72 + quad * 8));
      pf[3] = *(const bf16x8*)(lPw + (l16 * 72 + 32 + quad * 8));

      // ---- O += P V
#pragma unroll
      for (int kc2 = 0; kc2 < 4; ++kc2) {
#pragma unroll
        for (int db = 0; db < 8; ++db) {
          bf16x8 vf = *(const bf16x8*)(lV + ((db * 16 + l16) * 132 + kc2 * 32 + quad * 8));
          accO[db] = MFMA(pf[kc2], vf, accO[db]);
        }
      }
      __syncthreads();
    }

    // ---- epilogue
#pragma unroll
    for (int r = 0; r < 4; ++r) {
      const float inv = 1.0f / l_i[r];
      const int srow = q0 + wave * 16 + quad * 4 + r;
      u16* orow = O + ((size_t)b * 2048 + srow) * 2048 + h * 128;
#pragma unroll
      for (int db = 0; db < 8; ++db)
        orow[db * 16 + l16] = f2b(accO[db][r] * inv);
    }
  }
}

// ---------------------------------------------------------------------------
// Workspace (64 MiB): B0 = xb -> Ob alias, B1=Qb, B2=Kb, B3=Vb.
// wq/wk/wv transposed (25.2 MB) live in d_out (33.5 MB fp32, overwritten by
// gemm_out at the end); woT in Kb (dead after attn).
// ---------------------------------------------------------------------------
extern "C" void kernel_launch(void* const* d_in, const int* in_sizes, int n_in,
                              void* d_out, int out_size, void* d_ws, size_t ws_size,
                              hipStream_t stream) {
  const float* x  = (const float*)d_in[0];
  const float* fc = (const float*)d_in[1];
  const float* fs = (const float*)d_in[2];
  const float* wq = (const float*)d_in[3];
  const float* wk = (const float*)d_in[4];
  const float* wv = (const float*)d_in[5];
  const float* wo = (const float*)d_in[6];
  float* out = (float*)d_out;

  u16* ws = (u16*)d_ws;
  const size_t BUF = (size_t)4096 * 2048;
  u16* xb  = ws;
  u16* Ob  = ws;            // reuse B0 (xb dead after gemm_qkv)
  u16* Qb  = ws + 1 * BUF;
  u16* Kb  = ws + 2 * BUF;
  u16* Vb  = ws + 3 * BUF;
  u16* wTall = (u16*)d_out; // 6144*2048 bf16 = 25.2 MB scratch in d_out
  u16* woT = Kb;            // wo transpose (Kb dead after attn)

  hipLaunchKernelGGL(cvt_x, dim3(8192), dim3(256), 0, stream, x, xb);
  hipLaunchKernelGGL(wtrans3, dim3(32, 32, 3), dim3(256), 0, stream, wq, wk, wv, wTall);
  hipLaunchKernelGGL(gemm_qkv, dim3(48, 32), dim3(256), 0, stream, xb, wTall, Qb);
  hipLaunchKernelGGL(rope_kernel, dim3(16384), dim3(256), 0, stream, Qb, Kb, fc, fs);
  hipLaunchKernelGGL(attn3, dim3(16, 32), dim3(256), 0, stream, Qb, Kb, Vb, Ob);
  hipLaunchKernelGGL(wtrans_f32, dim3(32, 32), dim3(256), 0, stream, wo, woT);
  hipLaunchKernelGGL(gemm_out, dim3(16, 32), dim3(256), 0, stream, Ob, woT, out);
}

// Round 4
// 393.520 us; speedup vs baseline: 1.1887x; 1.0644x over previous
//
#include <hip/hip_runtime.h>

typedef unsigned short u16;
typedef unsigned int u32;
typedef __attribute__((ext_vector_type(8))) short bf16x8;
typedef __attribute__((ext_vector_type(4))) short bf16x4;
typedef __attribute__((ext_vector_type(4))) float f32x4;
typedef __attribute__((ext_vector_type(16))) float f32x16;

#define MFMA(a, b, c) __builtin_amdgcn_mfma_f32_16x16x32_bf16(a, b, c, 0, 0, 0)
#define MFMA32(a, b, c) __builtin_amdgcn_mfma_f32_32x32x16_bf16(a, b, c, 0, 0, 0)
#define ASYNC16(g, l)                                                        \
  __builtin_amdgcn_global_load_lds(                                          \
      (const __attribute__((address_space(1))) u32*)(g),                     \
      (__attribute__((address_space(3))) u32*)(l), 16, 0, 0)

__device__ __forceinline__ float b2f(u16 u) {
  union { u32 i; float f; } x; x.i = ((u32)u) << 16; return x.f;
}
__device__ __forceinline__ u16 f2b(float f) {
  union { float f; u32 i; } x; x.f = f;
  return (u16)((x.i + 0x7fff + ((x.i >> 16) & 1)) >> 16);
}
__device__ __forceinline__ f32x4 fzero4() { f32x4 z = {0.f, 0.f, 0.f, 0.f}; return z; }
__device__ __forceinline__ f32x16 fzero16() {
  f32x16 z;
#pragma unroll
  for (int i = 0; i < 16; ++i) z[i] = 0.f;
  return z;
}
// v_cvt_pk_bf16_f32: dst.lo16 = bf16(lo), dst.hi16 = bf16(hi)
__device__ __forceinline__ u32 pkbf16(float lo, float hi) {
  u32 r;
  asm("v_cvt_pk_bf16_f32 %0, %1, %2" : "=v"(r) : "v"(lo), "v"(hi));
  return r;
}

// ---------------------------------------------------------------------------
// x fp32 [4096*2048] -> bf16
// ---------------------------------------------------------------------------
__global__ __launch_bounds__(256) void cvt_x(const float* __restrict__ src,
                                             u16* __restrict__ dst) {
  const int i = (blockIdx.x * 256 + threadIdx.x) * 4;
  const f32x4 v = *(const f32x4*)(src + i);
  bf16x4 o;
  o[0] = (short)f2b(v[0]); o[1] = (short)f2b(v[1]);
  o[2] = (short)f2b(v[2]); o[3] = (short)f2b(v[3]);
  *(bf16x4*)(dst + i) = o;
}

// ---------------------------------------------------------------------------
// Weight transpose + cast (single): W fp32 [K][N] -> WT bf16 [N][K].
// ---------------------------------------------------------------------------
__global__ __launch_bounds__(256) void wtrans_f32(const float* __restrict__ src,
                                                  u16* __restrict__ dst) {
  __shared__ u16 tile[64][65];
  const int k0 = blockIdx.y * 64, n0 = blockIdx.x * 64;
  const int t = threadIdx.x;
  const int tr = t >> 3, tc = t & 7;

#pragma unroll
  for (int hh = 0; hh < 2; ++hh) {
    const int k = tr + hh * 32;
    const float* p = src + (size_t)(k0 + k) * 2048 + n0 + tc * 8;
    const f32x4 a = *(const f32x4*)(p);
    const f32x4 b = *(const f32x4*)(p + 4);
#pragma unroll
    for (int j = 0; j < 4; ++j) tile[k][tc * 8 + j] = f2b(a[j]);
#pragma unroll
    for (int j = 0; j < 4; ++j) tile[k][tc * 8 + 4 + j] = f2b(b[j]);
  }
  __syncthreads();
#pragma unroll
  for (int hh = 0; hh < 2; ++hh) {
    const int n = tr + hh * 32;
    bf16x8 v;
#pragma unroll
    for (int j = 0; j < 8; ++j) v[j] = (short)tile[tc * 8 + j][n];
    *(bf16x8*)(dst + (size_t)(n0 + n) * 2048 + k0 + tc * 8) = v;
  }
}

// z-indexed variant: z=0,1,2 -> wq,wk,wv into wTall + z*2048*2048.
__global__ __launch_bounds__(256) void wtrans3(const float* __restrict__ wq,
                                               const float* __restrict__ wk,
                                               const float* __restrict__ wv,
                                               u16* __restrict__ wTall) {
  __shared__ u16 tile[64][65];
  const int z = blockIdx.z;
  const float* src = (z == 0) ? wq : (z == 1) ? wk : wv;
  u16* dst = wTall + (size_t)z * 2048 * 2048;
  const int k0 = blockIdx.y * 64, n0 = blockIdx.x * 64;
  const int t = threadIdx.x;
  const int tr = t >> 3, tc = t & 7;

#pragma unroll
  for (int hh = 0; hh < 2; ++hh) {
    const int k = tr + hh * 32;
    const float* p = src + (size_t)(k0 + k) * 2048 + n0 + tc * 8;
    const f32x4 a = *(const f32x4*)(p);
    const f32x4 b = *(const f32x4*)(p + 4);
#pragma unroll
    for (int j = 0; j < 4; ++j) tile[k][tc * 8 + j] = f2b(a[j]);
#pragma unroll
    for (int j = 0; j < 4; ++j) tile[k][tc * 8 + 4 + j] = f2b(b[j]);
  }
  __syncthreads();
#pragma unroll
  for (int hh = 0; hh < 2; ++hh) {
    const int n = tr + hh * 32;
    bf16x8 v;
#pragma unroll
    for (int j = 0; j < 8; ++j) v[j] = (short)tile[tc * 8 + j][n];
    *(bf16x8*)(dst + (size_t)(n0 + n) * 2048 + k0 + tc * 8) = v;
  }
}

// ---------------------------------------------------------------------------
// Shared GEMM mainloop (m97 structure — proven 127 us / 811 TF on qkv).
// ---------------------------------------------------------------------------
__device__ __forceinline__ void gemm_mainloop(const u16* __restrict__ A,
                                              const u16* __restrict__ Bt,
                                              int K, int m0, int n0,
                                              u16* lA, u16* lB,
                                              f32x4 acc[4][4]) {
  const int tid = threadIdx.x;
  const int lane = tid & 63;
  const int wave = tid >> 6;
  const int quad = lane >> 4;
  const int l16 = lane & 15;
  const int wr = wave >> 1, wc = wave & 1;

  const int srow = lane >> 2;
  const int scol = (lane & 3) * 8;
  const u16* ga0 = A + (size_t)(m0 + (wave * 2 + 0) * 16 + srow) * K + scol;
  const u16* ga1 = A + (size_t)(m0 + (wave * 2 + 1) * 16 + srow) * K + scol;
  const u16* gb0 = Bt + (size_t)(n0 + (wave * 2 + 0) * 16 + srow) * K + scol;
  const u16* gb1 = Bt + (size_t)(n0 + (wave * 2 + 1) * 16 + srow) * K + scol;
  u16* la0 = lA + (wave * 2 + 0) * 512;
  u16* la1 = lA + (wave * 2 + 1) * 512;
  u16* lb0 = lB + (wave * 2 + 0) * 512;
  u16* lb1 = lB + (wave * 2 + 1) * 512;

  for (int k0 = 0; k0 < K; k0 += 32) {
    ASYNC16(ga0 + k0, la0);
    ASYNC16(ga1 + k0, la1);
    ASYNC16(gb0 + k0, lb0);
    ASYNC16(gb1 + k0, lb1);
    __syncthreads();
    bf16x8 af[4], bfr[4];
#pragma unroll
    for (int mb = 0; mb < 4; ++mb)
      af[mb] = *(const bf16x8*)(lA + ((wr * 64 + mb * 16 + l16) * 32 + quad * 8));
#pragma unroll
    for (int nb = 0; nb < 4; ++nb)
      bfr[nb] = *(const bf16x8*)(lB + ((wc * 64 + nb * 16 + l16) * 32 + quad * 8));
#pragma unroll
    for (int mb = 0; mb < 4; ++mb)
#pragma unroll
      for (int nb = 0; nb < 4; ++nb)
        acc[mb][nb] = MFMA(af[mb], bfr[nb], acc[mb][nb]);
    __syncthreads();
  }
}

// x[4096,2048] @ wTall[6144,2048]^T -> Q/K/V (consecutive BUF-sized buffers).
__global__ __launch_bounds__(256) void gemm_qkv(const u16* __restrict__ x,
                                                const u16* __restrict__ wT,
                                                u16* __restrict__ qkv) {
  __shared__ u16 lA[128 * 32];
  __shared__ u16 lB[128 * 32];
  f32x4 acc[4][4];
#pragma unroll
  for (int i = 0; i < 4; ++i)
#pragma unroll
    for (int j = 0; j < 4; ++j) acc[i][j] = fzero4();

  const int m0 = blockIdx.y * 128, n0 = blockIdx.x * 128;
  gemm_mainloop(x, wT, 2048, m0, n0, lA, lB, acc);

  const int lane = threadIdx.x & 63, wave = threadIdx.x >> 6;
  const int quad = lane >> 4, l16 = lane & 15;
  const int wr = wave >> 1, wc = wave & 1;
#pragma unroll
  for (int mb = 0; mb < 4; ++mb)
#pragma unroll
    for (int nb = 0; nb < 4; ++nb)
#pragma unroll
      for (int r = 0; r < 4; ++r) {
        const int row = m0 + wr * 64 + mb * 16 + quad * 4 + r;  // 0..4095
        const int col = n0 + wc * 64 + nb * 16 + l16;           // 0..6143
        const int b = row >> 11, s = row & 2047;
        const int which = col >> 11, rem = col & 2047;
        const int hh = rem >> 7, d = rem & 127;
        const size_t idx = (size_t)which * ((size_t)4096 * 2048) +
                           (((size_t)(b * 16 + hh) * 2048 + s) * 128 + d);
        qkv[idx] = f2b(acc[mb][nb][r]);
      }
}

// O[4096,2048] @ woT^T -> out fp32 [4096,2048]
__global__ __launch_bounds__(256) void gemm_out(const u16* __restrict__ Oin,
                                                const u16* __restrict__ woT,
                                                float* __restrict__ out) {
  __shared__ u16 lA[128 * 32];
  __shared__ u16 lB[128 * 32];
  f32x4 acc[4][4];
#pragma unroll
  for (int i = 0; i < 4; ++i)
#pragma unroll
    for (int j = 0; j < 4; ++j) acc[i][j] = fzero4();

  const int m0 = blockIdx.y * 128, n0 = blockIdx.x * 128;
  gemm_mainloop(Oin, woT, 2048, m0, n0, lA, lB, acc);

  const int lane = threadIdx.x & 63, wave = threadIdx.x >> 6;
  const int quad = lane >> 4, l16 = lane & 15;
  const int wr = wave >> 1, wc = wave & 1;
#pragma unroll
  for (int mb = 0; mb < 4; ++mb)
#pragma unroll
    for (int nb = 0; nb < 4; ++nb)
#pragma unroll
      for (int r = 0; r < 4; ++r) {
        const int row = m0 + wr * 64 + mb * 16 + quad * 4 + r;
        const int col = n0 + wc * 64 + nb * 16 + l16;
        out[(size_t)row * 2048 + col] = acc[mb][nb][r];
      }
}

// ---------------------------------------------------------------------------
// RoPE in place on Q and K; folds 1/sqrt(128) into Q.
// ---------------------------------------------------------------------------
__global__ __launch_bounds__(256) void rope_kernel(u16* __restrict__ Q,
                                                   u16* __restrict__ K,
                                                   const float* __restrict__ fcos,
                                                   const float* __restrict__ fsin) {
  const int i = blockIdx.x * 256 + threadIdx.x;
  const int d = i & 63;
  const int s = (i >> 6) & 2047;
  const int bh = i >> 17;
  const size_t base = ((size_t)bh * 2048 + s) * 128;
  const float c = fcos[s * 64 + d];
  const float sn = fsin[s * 64 + d];
  const float qs = 0.08838834764831845f;

  const float q0 = b2f(Q[base + d]), q1 = b2f(Q[base + d + 64]);
  Q[base + d] = f2b((q0 * c - q1 * sn) * qs);
  Q[base + d + 64] = f2b((q1 * c + q0 * sn) * qs);
  const float k0 = b2f(K[base + d]), k1 = b2f(K[base + d + 64]);
  K[base + d] = f2b(k0 * c - k1 * sn);
  K[base + d + 64] = f2b(k1 * c + k0 * sn);
}

// ---------------------------------------------------------------------------
// Flash attention v4: 32x32x16 MFMA, 32 q-rows/wave (BM=128/block), BN=64.
// Swapped QK^T (S^T = mfma(K, Q)) makes the softmax n-axis lane-local:
// in-register softmax (16 regs + one shfl_xor(32)); P converted in-register
// (v_cvt_pk_bf16_f32 + cross-half shfl_xor) straight into the PV A-fragment
// -> P never touches LDS.  LDS pads (136 / 72 u16) give odd-x16B row strides
// so 32-row b128 fragment reads spread uniformly over bank quads.
// Grid 512 = 2 blocks/CU exact; bid map groups a head's tiles on one XCD and
// pairs tiles qt / 23-tq for breadth-first load balance.
// ---------------------------------------------------------------------------
// S^T C-layout (32x32): col = lane&31 = q, row(reg,hi) = (r&3)+8*(r>>2)+4*hi.
template <int NB>
__device__ __forceinline__ void qkt_block(f32x16& sv, int n0, int qlo, int hi,
                                          int c, const u16* lK,
                                          const bf16x8* qf) {
  const int lo = n0 + NB * 32;
  if (lo < qlo + 32) {
    sv = fzero16();
#pragma unroll
    for (int kc = 0; kc < 8; ++kc) {
      const bf16x8 kf =
          *(const bf16x8*)(lK + (NB * 32 + c) * 136 + kc * 16 + hi * 8);
      sv = MFMA32(kf, qf[kc], sv);
    }
    if (lo == qlo) {  // diagonal 32x32: mask n32 > q32
#pragma unroll
      for (int r = 0; r < 16; ++r) {
        const int n32 = (r & 3) + 8 * (r >> 2) + 4 * hi;
        if (n32 > c) sv[r] = -1e30f;
      }
    }
  } else {
#pragma unroll
    for (int r = 0; r < 16; ++r) sv[r] = -1e30f;
  }
}

template <int NB>
__device__ __forceinline__ void pv_block(const f32x16& sv, int n0, int qlo,
                                         int hi, int c, const u16* lV,
                                         f32x16* accO) {
  if (n0 + NB * 32 < qlo + 32) {
#pragma unroll
    for (int half = 0; half < 2; ++half) {
      // pack P (f32, n-indexed regs) into PV A-frag: lane holds
      // A[row=q=c][k = hi*8 + j], k = n within this 16-chunk.
      const int rb = half * 8;
      const u32 pA = pkbf16(sv[rb + 0], sv[rb + 1]);
      const u32 pB = pkbf16(sv[rb + 2], sv[rb + 3]);
      const u32 pC = pkbf16(sv[rb + 4], sv[rb + 5]);
      const u32 pD = pkbf16(sv[rb + 6], sv[rb + 7]);
      const u32 xA = (u32)__shfl_xor((int)pA, 32);
      const u32 xB = (u32)__shfl_xor((int)pB, 32);
      const u32 xC = (u32)__shfl_xor((int)pC, 32);
      const u32 xD = (u32)__shfl_xor((int)pD, 32);
      bf16x8 pa;
      u32* pw = (u32*)&pa;
      pw[0] = hi ? xC : pA;
      pw[1] = hi ? xD : pB;
      pw[2] = hi ? pC : xA;
      pw[3] = hi ? pD : xB;
#pragma unroll
      for (int db = 0; db < 4; ++db) {
        const bf16x8 vf = *(const bf16x8*)(lV + (db * 32 + c) * 72 +
                                           NB * 32 + half * 16 + hi * 8);
        accO[db] = MFMA32(pa, vf, accO[db]);
      }
    }
  }
}

__global__ __launch_bounds__(256, 2) void attn4(const u16* __restrict__ Q,
                                                const u16* __restrict__ K,
                                                const u16* __restrict__ V,
                                                u16* __restrict__ O) {
  __shared__ u16 lK[64 * 136];   // K-tile [n][d], stride 272B (odd x16B)
  __shared__ u16 lV[128 * 72];   // V^T    [d][n], stride 144B (odd x16B)

  const int bid = blockIdx.x;
  const int bh = (bid & 7) + 8 * ((bid >> 3) & 3);  // head-group per XCD
  const int tq = bid >> 5;
  const int qt = (tq < 8) ? tq : 23 - tq;           // pair qt with 15-qt
  const int q0 = qt * 128;
  const int b = bh >> 4, h = bh & 15;
  const u16* Qh = Q + (size_t)bh * 2048 * 128;
  const u16* Kh = K + (size_t)bh * 2048 * 128;
  const u16* Vh = V + (size_t)bh * 2048 * 128;

  const int tid = threadIdx.x;
  const int lane = tid & 63, wave = tid >> 6;
  const int hi = lane >> 5, c = lane & 31;
  const int qlo = q0 + wave * 32;
  // K staging: rows krow+16i (i<4), 16B d-chunk kj
  const int krow = tid >> 4, kj = tid & 15;
  // V staging: n-rows r0, r0+1; d-chunk d0v..d0v+15
  const int r0 = (tid & 31) * 2, d0v = (tid >> 5) * 16;

  // Q fragments (B-operand): lane holds Q[q0+wave*32+c][kc*16 + hi*8 + j]
  bf16x8 qf[8];
  {
    const u16* qrow = Qh + (size_t)(q0 + wave * 32 + c) * 128 + hi * 8;
#pragma unroll
    for (int kc = 0; kc < 8; ++kc) qf[kc] = *(const bf16x8*)(qrow + kc * 16);
  }

  float m_i = -1e30f, l_i = 0.f;
  f32x16 accO[4];
#pragma unroll
  for (int db = 0; db < 4; ++db) accO[db] = fzero16();

  const int nIter = 2 * qt + 2;

  bf16x8 kreg[4], vreg[4];
  // prefetch first tile
  {
#pragma unroll
    for (int i = 0; i < 4; ++i)
      kreg[i] = *(const bf16x8*)(Kh + (size_t)(krow + 16 * i) * 128 + kj * 8);
    const u16* vp = Vh + (size_t)r0 * 128 + d0v;
    vreg[0] = *(const bf16x8*)(vp);
    vreg[1] = *(const bf16x8*)(vp + 8);
    vreg[2] = *(const bf16x8*)(vp + 128);
    vreg[3] = *(const bf16x8*)(vp + 136);
  }

  for (int it = 0; it < nIter; ++it) {
    const int n0 = it * 64;
    // ---- staged regs -> LDS
#pragma unroll
    for (int i = 0; i < 4; ++i)
      *(bf16x8*)(lK + (krow + 16 * i) * 136 + kj * 8) = kreg[i];
#pragma unroll
    for (int j = 0; j < 8; ++j) {
      const u32 lo = (u16)vreg[0][j], hi2 = (u16)vreg[2][j];
      *(u32*)(lV + (d0v + j) * 72 + r0) = lo | (hi2 << 16);
    }
#pragma unroll
    for (int j = 0; j < 8; ++j) {
      const u32 lo = (u16)vreg[1][j], hi2 = (u16)vreg[3][j];
      *(u32*)(lV + (d0v + 8 + j) * 72 + r0) = lo | (hi2 << 16);
    }
    __syncthreads();

    // ---- prefetch next tile (overlaps compute)
    if (it + 1 < nIter) {
      const int nn = n0 + 64;
#pragma unroll
      for (int i = 0; i < 4; ++i)
        kreg[i] =
            *(const bf16x8*)(Kh + (size_t)(nn + krow + 16 * i) * 128 + kj * 8);
      const u16* vp = Vh + (size_t)(nn + r0) * 128 + d0v;
      vreg[0] = *(const bf16x8*)(vp);
      vreg[1] = *(const bf16x8*)(vp + 8);
      vreg[2] = *(const bf16x8*)(vp + 128);
      vreg[3] = *(const bf16x8*)(vp + 136);
    }

    // ---- S^T = K Q^T (swapped): lane holds S[n][q=c], n via (reg,hi)
    f32x16 s0, s1;
    qkt_block<0>(s0, n0, qlo, hi, c, lK, qf);
    qkt_block<1>(s1, n0, qlo, hi, c, lK, qf);

    // ---- online softmax, fully in-register (reduce over n)
    float mx = -1e30f;
#pragma unroll
    for (int r = 0; r < 16; ++r) mx = fmaxf(mx, fmaxf(s0[r], s1[r]));
    mx = fmaxf(mx, __shfl_xor(mx, 32));
    const float mn = fmaxf(m_i, mx);
    const float alpha = __expf(m_i - mn);
    m_i = mn;
    float rs = 0.f;
#pragma unroll
    for (int r = 0; r < 16; ++r) {
      const float p0 = __expf(s0[r] - mn);
      const float p1 = __expf(s1[r] - mn);
      s0[r] = p0; s1[r] = p1;
      rs += p0 + p1;
    }
    rs += __shfl_xor(rs, 32);
    l_i = l_i * alpha + rs;

    // ---- rescale accO (alpha redistributed lane[q] -> C-layout rows)
#pragma unroll
    for (int r = 0; r < 16; ++r) {
      const int src = ((r & 3) + 8 * (r >> 2) + 4 * hi) + (lane & 32);
      const float aa = __shfl(alpha, src);
      accO[0][r] *= aa; accO[1][r] *= aa;
      accO[2][r] *= aa; accO[3][r] *= aa;
    }

    // ---- O += P V
    pv_block<0>(s0, n0, qlo, hi, c, lV, accO);
    pv_block<1>(s1, n0, qlo, hi, c, lV, accO);
    __syncthreads();
  }

  // ---- epilogue
  const float linv = 1.f / l_i;
#pragma unroll
  for (int r = 0; r < 16; ++r) {
    const int q32 = (r & 3) + 8 * (r >> 2) + 4 * hi;
    const float inv = __shfl(linv, q32 + (lane & 32));
    const int srow = q0 + wave * 32 + q32;
    u16* orow = O + ((size_t)b * 2048 + srow) * 2048 + h * 128 + c;
#pragma unroll
    for (int db = 0; db < 4; ++db) orow[db * 32] = f2b(accO[db][r] * inv);
  }
}

// ---------------------------------------------------------------------------
// Workspace (64 MiB): B0 = xb -> Ob alias, B1=Qb, B2=Kb, B3=Vb.
// wq/wk/wv transposed (25.2 MB) live in d_out (33.5 MB fp32, overwritten by
// gemm_out at the end); woT in Kb (dead after attn).
// ---------------------------------------------------------------------------
extern "C" void kernel_launch(void* const* d_in, const int* in_sizes, int n_in,
                              void* d_out, int out_size, void* d_ws, size_t ws_size,
                              hipStream_t stream) {
  const float* x  = (const float*)d_in[0];
  const float* fc = (const float*)d_in[1];
  const float* fs = (const float*)d_in[2];
  const float* wq = (const float*)d_in[3];
  const float* wk = (const float*)d_in[4];
  const float* wv = (const float*)d_in[5];
  const float* wo = (const float*)d_in[6];
  float* out = (float*)d_out;

  u16* ws = (u16*)d_ws;
  const size_t BUF = (size_t)4096 * 2048;
  u16* xb  = ws;
  u16* Ob  = ws;            // reuse B0 (xb dead after gemm_qkv)
  u16* Qb  = ws + 1 * BUF;
  u16* Kb  = ws + 2 * BUF;
  u16* Vb  = ws + 3 * BUF;
  u16* wTall = (u16*)d_out; // 6144*2048 bf16 = 25.2 MB scratch in d_out
  u16* woT = Kb;            // wo transpose (Kb dead after attn)

  hipLaunchKernelGGL(cvt_x, dim3(8192), dim3(256), 0, stream, x, xb);
  hipLaunchKernelGGL(wtrans3, dim3(32, 32, 3), dim3(256), 0, stream, wq, wk, wv, wTall);
  hipLaunchKernelGGL(gemm_qkv, dim3(48, 32), dim3(256), 0, stream, xb, wTall, Qb);
  hipLaunchKernelGGL(rope_kernel, dim3(16384), dim3(256), 0, stream, Qb, Kb, fc, fs);
  hipLaunchKernelGGL(attn4, dim3(512), dim3(256), 0, stream, Qb, Kb, Vb, Ob);
  hipLaunchKernelGGL(wtrans_f32, dim3(32, 32), dim3(256), 0, stream, wo, woT);
  hipLaunchKernelGGL(gemm_out, dim3(16, 32), dim3(256), 0, stream, Ob, woT, out);
}

// Round 5
// 388.897 us; speedup vs baseline: 1.2028x; 1.0119x over previous
//
#include <hip/hip_runtime.h>

typedef unsigned short u16;
typedef unsigned int u32;
typedef __attribute__((ext_vector_type(8))) short bf16x8;
typedef __attribute__((ext_vector_type(4))) short bf16x4;
typedef __attribute__((ext_vector_type(4))) float f32x4;
typedef __attribute__((ext_vector_type(16))) float f32x16;

#define MFMA(a, b, c) __builtin_amdgcn_mfma_f32_16x16x32_bf16(a, b, c, 0, 0, 0)
#define MFMA32(a, b, c) __builtin_amdgcn_mfma_f32_32x32x16_bf16(a, b, c, 0, 0, 0)
#define ASYNC16(g, l)                                                        \
  __builtin_amdgcn_global_load_lds(                                          \
      (const __attribute__((address_space(1))) u32*)(g),                     \
      (__attribute__((address_space(3))) u32*)(l), 16, 0, 0)

#define SBARRIER()                                                           \
  do {                                                                       \
    asm volatile("" ::: "memory");                                           \
    __builtin_amdgcn_s_barrier();                                            \
    asm volatile("" ::: "memory");                                           \
  } while (0)

__device__ __forceinline__ float b2f(u16 u) {
  union { u32 i; float f; } x; x.i = ((u32)u) << 16; return x.f;
}
__device__ __forceinline__ u16 f2b(float f) {
  union { float f; u32 i; } x; x.f = f;
  return (u16)((x.i + 0x7fff + ((x.i >> 16) & 1)) >> 16);
}
__device__ __forceinline__ f32x4 fzero4() { f32x4 z = {0.f, 0.f, 0.f, 0.f}; return z; }
__device__ __forceinline__ f32x16 fzero16() {
  f32x16 z;
#pragma unroll
  for (int i = 0; i < 16; ++i) z[i] = 0.f;
  return z;
}
// v_cvt_pk_bf16_f32: dst.lo16 = bf16(lo), dst.hi16 = bf16(hi)
__device__ __forceinline__ u32 pkbf16(float lo, float hi) {
  u32 r;
  asm("v_cvt_pk_bf16_f32 %0, %1, %2" : "=v"(r) : "v"(lo), "v"(hi));
  return r;
}

// ---------------------------------------------------------------------------
// x fp32 [4096*2048] -> bf16
// ---------------------------------------------------------------------------
__global__ __launch_bounds__(256) void cvt_x(const float* __restrict__ src,
                                             u16* __restrict__ dst) {
  const int i = (blockIdx.x * 256 + threadIdx.x) * 4;
  const f32x4 v = *(const f32x4*)(src + i);
  bf16x4 o;
  o[0] = (short)f2b(v[0]); o[1] = (short)f2b(v[1]);
  o[2] = (short)f2b(v[2]); o[3] = (short)f2b(v[3]);
  *(bf16x4*)(dst + i) = o;
}

// ---------------------------------------------------------------------------
// Weight transpose + cast (single): W fp32 [K][N] -> WT bf16 [N][K].
// ---------------------------------------------------------------------------
__global__ __launch_bounds__(256) void wtrans_f32(const float* __restrict__ src,
                                                  u16* __restrict__ dst) {
  __shared__ u16 tile[64][65];
  const int k0 = blockIdx.y * 64, n0 = blockIdx.x * 64;
  const int t = threadIdx.x;
  const int tr = t >> 3, tc = t & 7;

#pragma unroll
  for (int hh = 0; hh < 2; ++hh) {
    const int k = tr + hh * 32;
    const float* p = src + (size_t)(k0 + k) * 2048 + n0 + tc * 8;
    const f32x4 a = *(const f32x4*)(p);
    const f32x4 b = *(const f32x4*)(p + 4);
#pragma unroll
    for (int j = 0; j < 4; ++j) tile[k][tc * 8 + j] = f2b(a[j]);
#pragma unroll
    for (int j = 0; j < 4; ++j) tile[k][tc * 8 + 4 + j] = f2b(b[j]);
  }
  __syncthreads();
#pragma unroll
  for (int hh = 0; hh < 2; ++hh) {
    const int n = tr + hh * 32;
    bf16x8 v;
#pragma unroll
    for (int j = 0; j < 8; ++j) v[j] = (short)tile[tc * 8 + j][n];
    *(bf16x8*)(dst + (size_t)(n0 + n) * 2048 + k0 + tc * 8) = v;
  }
}

// z-indexed variant: z=0,1,2 -> wq,wk,wv into wTall + z*2048*2048.
__global__ __launch_bounds__(256) void wtrans3(const float* __restrict__ wq,
                                               const float* __restrict__ wk,
                                               const float* __restrict__ wv,
                                               u16* __restrict__ wTall) {
  __shared__ u16 tile[64][65];
  const int z = blockIdx.z;
  const float* src = (z == 0) ? wq : (z == 1) ? wk : wv;
  u16* dst = wTall + (size_t)z * 2048 * 2048;
  const int k0 = blockIdx.y * 64, n0 = blockIdx.x * 64;
  const int t = threadIdx.x;
  const int tr = t >> 3, tc = t & 7;

#pragma unroll
  for (int hh = 0; hh < 2; ++hh) {
    const int k = tr + hh * 32;
    const float* p = src + (size_t)(k0 + k) * 2048 + n0 + tc * 8;
    const f32x4 a = *(const f32x4*)(p);
    const f32x4 b = *(const f32x4*)(p + 4);
#pragma unroll
    for (int j = 0; j < 4; ++j) tile[k][tc * 8 + j] = f2b(a[j]);
#pragma unroll
    for (int j = 0; j < 4; ++j) tile[k][tc * 8 + 4 + j] = f2b(b[j]);
  }
  __syncthreads();
#pragma unroll
  for (int hh = 0; hh < 2; ++hh) {
    const int n = tr + hh * 32;
    bf16x8 v;
#pragma unroll
    for (int j = 0; j < 8; ++j) v[j] = (short)tile[tc * 8 + j][n];
    *(bf16x8*)(dst + (size_t)(n0 + n) * 2048 + k0 + tc * 8) = v;
  }
}

// ---------------------------------------------------------------------------
// Shared GEMM mainloop (m97 structure — proven 127 us / 811 TF on qkv).
// ---------------------------------------------------------------------------
__device__ __forceinline__ void gemm_mainloop(const u16* __restrict__ A,
                                              const u16* __restrict__ Bt,
                                              int K, int m0, int n0,
                                              u16* lA, u16* lB,
                                              f32x4 acc[4][4]) {
  const int tid = threadIdx.x;
  const int lane = tid & 63;
  const int wave = tid >> 6;
  const int quad = lane >> 4;
  const int l16 = lane & 15;
  const int wr = wave >> 1, wc = wave & 1;

  const int srow = lane >> 2;
  const int scol = (lane & 3) * 8;
  const u16* ga0 = A + (size_t)(m0 + (wave * 2 + 0) * 16 + srow) * K + scol;
  const u16* ga1 = A + (size_t)(m0 + (wave * 2 + 1) * 16 + srow) * K + scol;
  const u16* gb0 = Bt + (size_t)(n0 + (wave * 2 + 0) * 16 + srow) * K + scol;
  const u16* gb1 = Bt + (size_t)(n0 + (wave * 2 + 1) * 16 + srow) * K + scol;
  u16* la0 = lA + (wave * 2 + 0) * 512;
  u16* la1 = lA + (wave * 2 + 1) * 512;
  u16* lb0 = lB + (wave * 2 + 0) * 512;
  u16* lb1 = lB + (wave * 2 + 1) * 512;

  for (int k0 = 0; k0 < K; k0 += 32) {
    ASYNC16(ga0 + k0, la0);
    ASYNC16(ga1 + k0, la1);
    ASYNC16(gb0 + k0, lb0);
    ASYNC16(gb1 + k0, lb1);
    __syncthreads();
    bf16x8 af[4], bfr[4];
#pragma unroll
    for (int mb = 0; mb < 4; ++mb)
      af[mb] = *(const bf16x8*)(lA + ((wr * 64 + mb * 16 + l16) * 32 + quad * 8));
#pragma unroll
    for (int nb = 0; nb < 4; ++nb)
      bfr[nb] = *(const bf16x8*)(lB + ((wc * 64 + nb * 16 + l16) * 32 + quad * 8));
#pragma unroll
    for (int mb = 0; mb < 4; ++mb)
#pragma unroll
      for (int nb = 0; nb < 4; ++nb)
        acc[mb][nb] = MFMA(af[mb], bfr[nb], acc[mb][nb]);
    __syncthreads();
  }
}

// x[4096,2048] @ wTall[6144,2048]^T -> Q/K/V (consecutive BUF-sized buffers).
__global__ __launch_bounds__(256) void gemm_qkv(const u16* __restrict__ x,
                                                const u16* __restrict__ wT,
                                                u16* __restrict__ qkv) {
  __shared__ u16 lA[128 * 32];
  __shared__ u16 lB[128 * 32];
  f32x4 acc[4][4];
#pragma unroll
  for (int i = 0; i < 4; ++i)
#pragma unroll
    for (int j = 0; j < 4; ++j) acc[i][j] = fzero4();

  const int m0 = blockIdx.y * 128, n0 = blockIdx.x * 128;
  gemm_mainloop(x, wT, 2048, m0, n0, lA, lB, acc);

  const int lane = threadIdx.x & 63, wave = threadIdx.x >> 6;
  const int quad = lane >> 4, l16 = lane & 15;
  const int wr = wave >> 1, wc = wave & 1;
#pragma unroll
  for (int mb = 0; mb < 4; ++mb)
#pragma unroll
    for (int nb = 0; nb < 4; ++nb)
#pragma unroll
      for (int r = 0; r < 4; ++r) {
        const int row = m0 + wr * 64 + mb * 16 + quad * 4 + r;  // 0..4095
        const int col = n0 + wc * 64 + nb * 16 + l16;           // 0..6143
        const int b = row >> 11, s = row & 2047;
        const int which = col >> 11, rem = col & 2047;
        const int hh = rem >> 7, d = rem & 127;
        const size_t idx = (size_t)which * ((size_t)4096 * 2048) +
                           (((size_t)(b * 16 + hh) * 2048 + s) * 128 + d);
        qkv[idx] = f2b(acc[mb][nb][r]);
      }
}

// ---------------------------------------------------------------------------
// gemm_out8: O[4096,2048] @ woT^T -> out fp32, 8-phase-style deep pipeline.
// BM=256, BN=128, BK=64, 512 thr (8 waves 2Mx4N, per-wave 128x32).
// RING-3 LDS K-tile slots (48 KiB each, 144 KiB total): tile t+2 stages into
// the slot holding tile t-1 (provably dead behind the end-of-t-1 barrier) --
// fixes the round-1 dbuf-2 overwrite race.  Counted vmcnt(6) once per K-tile
// (never 0 in-loop): tile t+1's 6 loads may fly across all of tile t.
// XOR swizzle (chunk ^= row&7) applied BOTH sides (rule 21): inverse-swizzled
// per-lane GLOBAL source + linear LDS dest (global_load_lds), swizzled
// ds_read -> fragment reads are bank-uniform (8 words/bank = b128 floor).
// Grid 256 = exactly 1 block/CU, 1 full round.
// ---------------------------------------------------------------------------
__global__ __launch_bounds__(512, 2) void gemm_out8(const u16* __restrict__ Oin,
                                                    const u16* __restrict__ woT,
                                                    float* __restrict__ out) {
  __shared__ u16 lds[3 * 24576];  // slot: A[256][64] (16384 u16) + B[128][64] (8192)

  const int orig = blockIdx.x;  // 256 blocks, 256 % 8 == 0 -> bijective swizzle
  const int wg = (orig & 7) * 32 + (orig >> 3);
  const int m0 = (wg >> 4) * 256;
  const int n0 = (wg & 15) * 128;

  const int tid = threadIdx.x;
  const int lane = tid & 63;
  const int wave = tid >> 6;
  const int quad = lane >> 4, l16 = lane & 15;
  const int wr = wave >> 2, wc = wave & 3;  // 2 x 4 wave grid

  // staging: thread covers unit-chunks L0=tid, L1=tid+512 (unit = 128rx64k).
  // inverse-swizzled global column chunk: cc = (L&7) ^ ((L>>3)&7).
  const int r0s = tid >> 3;                // 0..63
  const int c0s = (tid & 7) ^ (r0s & 7);
  const int r1s = r0s + 64;                // 64..127
  const int c1s = (tid & 7) ^ (r1s & 7);

  const u16* gA = Oin + (size_t)m0 * 2048;
  const u16* gB = woT + (size_t)n0 * 2048;

#define SLOT8(t) (lds + ((t) % 3) * 24576)
#define STAGE_A8(t)                                                          \
  do {                                                                       \
    u16* Lb0 = SLOT8(t) + wave * 512;                                        \
    const u16* g0 = gA + (t) * 64;                                           \
    ASYNC16(g0 + (size_t)r0s * 2048 + c0s * 8, Lb0);                         \
    ASYNC16(g0 + (size_t)r1s * 2048 + c1s * 8, Lb0 + 4096);                  \
    u16* Lb1 = SLOT8(t) + 8192 + wave * 512;                                 \
    const u16* g1 = gA + (size_t)128 * 2048 + (t) * 64;                      \
    ASYNC16(g1 + (size_t)r0s * 2048 + c0s * 8, Lb1);                         \
    ASYNC16(g1 + (size_t)r1s * 2048 + c1s * 8, Lb1 + 4096);                  \
  } while (0)
#define STAGE_B8(t)                                                          \
  do {                                                                       \
    u16* Lb = SLOT8(t) + 16384 + wave * 512;                                 \
    const u16* g = gB + (t) * 64;                                            \
    ASYNC16(g + (size_t)r0s * 2048 + c0s * 8, Lb);                           \
    ASYNC16(g + (size_t)r1s * 2048 + c1s * 8, Lb + 4096);                    \
  } while (0)

  f32x4 acc[8][2];
#pragma unroll
  for (int i = 0; i < 8; ++i) { acc[i][0] = fzero4(); acc[i][1] = fzero4(); }

  // fragment read offsets (u16), swizzle hoisted: row&7 == l16&7 everywhere
  int aoff[8], boff[2];
#pragma unroll
  for (int mb = 0; mb < 8; ++mb) aoff[mb] = (wr * 128 + mb * 16 + l16) * 64;
#pragma unroll
  for (int nb = 0; nb < 2; ++nb) boff[nb] = 16384 + (wc * 32 + nb * 16 + l16) * 64;
  const int ach0 = ((0 * 4 + quad) ^ (l16 & 7)) * 8;  // kstep 0 chunk
  const int ach1 = ((1 * 4 + quad) ^ (l16 & 7)) * 8;  // kstep 1 chunk

  // prologue: stage tiles 0,1 (12 loads/wave), wait tile 0 (6 stay in flight)
  STAGE_A8(0); STAGE_B8(0);
  STAGE_A8(1); STAGE_B8(1);
  asm volatile("s_waitcnt vmcnt(6)" ::: "memory");
  SBARRIER();

  for (int t = 0; t < 32; ++t) {
    const u16* sl = SLOT8(t);
    bf16x8 af[8], bfr[2];

    // -------- phase A: kstep 0 (16 MFMA) --------
#pragma unroll
    for (int mb = 0; mb < 8; ++mb)
      af[mb] = *(const bf16x8*)(sl + aoff[mb] + ach0);
#pragma unroll
    for (int nb = 0; nb < 2; ++nb)
      bfr[nb] = *(const bf16x8*)(sl + boff[nb] + ach0);
    if (t < 30) STAGE_A8(t + 2);
    SBARRIER();
    asm volatile("s_waitcnt lgkmcnt(0)" ::: "memory");
    __builtin_amdgcn_s_setprio(1);
#pragma unroll
    for (int mb = 0; mb < 8; ++mb)
#pragma unroll
      for (int nb = 0; nb < 2; ++nb)
        acc[mb][nb] = MFMA(af[mb], bfr[nb], acc[mb][nb]);
    __builtin_amdgcn_s_setprio(0);
    SBARRIER();

    // -------- phase B: kstep 1 (16 MFMA) --------
#pragma unroll
    for (int mb = 0; mb < 8; ++mb)
      af[mb] = *(const bf16x8*)(sl + aoff[mb] + ach1);
#pragma unroll
    for (int nb = 0; nb < 2; ++nb)
      bfr[nb] = *(const bf16x8*)(sl + boff[nb] + ach1);
    if (t < 30) STAGE_B8(t + 2);
    SBARRIER();
    asm volatile("s_waitcnt lgkmcnt(0)" ::: "memory");
    __builtin_amdgcn_s_setprio(1);
#pragma unroll
    for (int mb = 0; mb < 8; ++mb)
#pragma unroll
      for (int nb = 0; nb < 2; ++nb)
        acc[mb][nb] = MFMA(af[mb], bfr[nb], acc[mb][nb]);
    __builtin_amdgcn_s_setprio(0);
    // per-K-tile counted wait: tile t+1 resident, tile t+2's 6 stay in flight
    if (t <= 29) {
      asm volatile("s_waitcnt vmcnt(6)" ::: "memory");
    } else if (t == 30) {
      asm volatile("s_waitcnt vmcnt(0)" ::: "memory");
    }
    SBARRIER();
  }
#undef SLOT8
#undef STAGE_A8
#undef STAGE_B8

  // epilogue: fp32 C-write
#pragma unroll
  for (int mb = 0; mb < 8; ++mb)
#pragma unroll
    for (int nb = 0; nb < 2; ++nb)
#pragma unroll
      for (int r = 0; r < 4; ++r) {
        const int row = m0 + wr * 128 + mb * 16 + quad * 4 + r;
        const int col = n0 + wc * 32 + nb * 16 + l16;
        out[(size_t)row * 2048 + col] = acc[mb][nb][r];
      }
}

// ---------------------------------------------------------------------------
// RoPE in place on Q and K; folds 1/sqrt(128) into Q.
// ---------------------------------------------------------------------------
__global__ __launch_bounds__(256) void rope_kernel(u16* __restrict__ Q,
                                                   u16* __restrict__ K,
                                                   const float* __restrict__ fcos,
                                                   const float* __restrict__ fsin) {
  const int i = blockIdx.x * 256 + threadIdx.x;
  const int d = i & 63;
  const int s = (i >> 6) & 2047;
  const int bh = i >> 17;
  const size_t base = ((size_t)bh * 2048 + s) * 128;
  const float c = fcos[s * 64 + d];
  const float sn = fsin[s * 64 + d];
  const float qs = 0.08838834764831845f;

  const float q0 = b2f(Q[base + d]), q1 = b2f(Q[base + d + 64]);
  Q[base + d] = f2b((q0 * c - q1 * sn) * qs);
  Q[base + d + 64] = f2b((q1 * c + q0 * sn) * qs);
  const float k0 = b2f(K[base + d]), k1 = b2f(K[base + d + 64]);
  K[base + d] = f2b(k0 * c - k1 * sn);
  K[base + d + 64] = f2b(k1 * c + k0 * sn);
}

// ---------------------------------------------------------------------------
// Flash attention v4 (+T13 defer-rescale, +T5 setprio this round).
// 32x32x16 MFMA, 32 q-rows/wave (BM=128/block), BN=64, swapped QK^T,
// in-register softmax, P packed in-register (cvt_pk + shfl_xor).
// ---------------------------------------------------------------------------
// S^T C-layout (32x32): col = lane&31 = q, row(reg,hi) = (r&3)+8*(r>>2)+4*hi.
template <int NB>
__device__ __forceinline__ void qkt_block(f32x16& sv, int n0, int qlo, int hi,
                                          int c, const u16* lK,
                                          const bf16x8* qf) {
  const int lo = n0 + NB * 32;
  if (lo < qlo + 32) {
    sv = fzero16();
    __builtin_amdgcn_s_setprio(1);
#pragma unroll
    for (int kc = 0; kc < 8; ++kc) {
      const bf16x8 kf =
          *(const bf16x8*)(lK + (NB * 32 + c) * 136 + kc * 16 + hi * 8);
      sv = MFMA32(kf, qf[kc], sv);
    }
    __builtin_amdgcn_s_setprio(0);
    if (lo == qlo) {  // diagonal 32x32: mask n32 > q32
#pragma unroll
      for (int r = 0; r < 16; ++r) {
        const int n32 = (r & 3) + 8 * (r >> 2) + 4 * hi;
        if (n32 > c) sv[r] = -1e30f;
      }
    }
  } else {
#pragma unroll
    for (int r = 0; r < 16; ++r) sv[r] = -1e30f;
  }
}

template <int NB>
__device__ __forceinline__ void pv_block(const f32x16& sv, int n0, int qlo,
                                         int hi, int c, const u16* lV,
                                         f32x16* accO) {
  if (n0 + NB * 32 < qlo + 32) {
#pragma unroll
    for (int half = 0; half < 2; ++half) {
      // pack P (f32, n-indexed regs) into PV A-frag: lane holds
      // A[row=q=c][k = hi*8 + j], k = n within this 16-chunk.
      const int rb = half * 8;
      const u32 pA = pkbf16(sv[rb + 0], sv[rb + 1]);
      const u32 pB = pkbf16(sv[rb + 2], sv[rb + 3]);
      const u32 pC = pkbf16(sv[rb + 4], sv[rb + 5]);
      const u32 pD = pkbf16(sv[rb + 6], sv[rb + 7]);
      const u32 xA = (u32)__shfl_xor((int)pA, 32);
      const u32 xB = (u32)__shfl_xor((int)pB, 32);
      const u32 xC = (u32)__shfl_xor((int)pC, 32);
      const u32 xD = (u32)__shfl_xor((int)pD, 32);
      bf16x8 pa;
      u32* pw = (u32*)&pa;
      pw[0] = hi ? xC : pA;
      pw[1] = hi ? xD : pB;
      pw[2] = hi ? pC : xA;
      pw[3] = hi ? pD : xB;
      __builtin_amdgcn_s_setprio(1);
#pragma unroll
      for (int db = 0; db < 4; ++db) {
        const bf16x8 vf = *(const bf16x8*)(lV + (db * 32 + c) * 72 +
                                           NB * 32 + half * 16 + hi * 8);
        accO[db] = MFMA32(pa, vf, accO[db]);
      }
      __builtin_amdgcn_s_setprio(0);
    }
  }
}

__global__ __launch_bounds__(256, 2) void attn4(const u16* __restrict__ Q,
                                                const u16* __restrict__ K,
                                                const u16* __restrict__ V,
                                                u16* __restrict__ O) {
  __shared__ u16 lK[64 * 136];   // K-tile [n][d], stride 272B (odd x16B)
  __shared__ u16 lV[128 * 72];   // V^T    [d][n], stride 144B (odd x16B)

  const int bid = blockIdx.x;
  const int bh = (bid & 7) + 8 * ((bid >> 3) & 3);  // head-group per XCD
  const int tq = bid >> 5;
  const int qt = (tq < 8) ? tq : 23 - tq;           // pair: per-CU 34 iters
  const int q0 = qt * 128;
  const int b = bh >> 4, h = bh & 15;
  const u16* Qh = Q + (size_t)bh * 2048 * 128;
  const u16* Kh = K + (size_t)bh * 2048 * 128;
  const u16* Vh = V + (size_t)bh * 2048 * 128;

  const int tid = threadIdx.x;
  const int lane = tid & 63, wave = tid >> 6;
  const int hi = lane >> 5, c = lane & 31;
  const int qlo = q0 + wave * 32;
  // K staging: rows krow+16i (i<4), 16B d-chunk kj
  const int krow = tid >> 4, kj = tid & 15;
  // V staging: n-rows r0, r0+1; d-chunk d0v..d0v+15
  const int r0 = (tid & 31) * 2, d0v = (tid >> 5) * 16;

  // Q fragments (B-operand): lane holds Q[q0+wave*32+c][kc*16 + hi*8 + j]
  bf16x8 qf[8];
  {
    const u16* qrow = Qh + (size_t)(q0 + wave * 32 + c) * 128 + hi * 8;
#pragma unroll
    for (int kc = 0; kc < 8; ++kc) qf[kc] = *(const bf16x8*)(qrow + kc * 16);
  }

  float m_i = -1e30f, l_i = 0.f;
  f32x16 accO[4];
#pragma unroll
  for (int db = 0; db < 4; ++db) accO[db] = fzero16();

  const int nIter = 2 * qt + 2;

  bf16x8 kreg[4], vreg[4];
  // prefetch first tile
  {
#pragma unroll
    for (int i = 0; i < 4; ++i)
      kreg[i] = *(const bf16x8*)(Kh + (size_t)(krow + 16 * i) * 128 + kj * 8);
    const u16* vp = Vh + (size_t)r0 * 128 + d0v;
    vreg[0] = *(const bf16x8*)(vp);
    vreg[1] = *(const bf16x8*)(vp + 8);
    vreg[2] = *(const bf16x8*)(vp + 128);
    vreg[3] = *(const bf16x8*)(vp + 136);
  }

  for (int it = 0; it < nIter; ++it) {
    const int n0 = it * 64;
    // ---- staged regs -> LDS
#pragma unroll
    for (int i = 0; i < 4; ++i)
      *(bf16x8*)(lK + (krow + 16 * i) * 136 + kj * 8) = kreg[i];
#pragma unroll
    for (int j = 0; j < 8; ++j) {
      const u32 lo = (u16)vreg[0][j], hi2 = (u16)vreg[2][j];
      *(u32*)(lV + (d0v + j) * 72 + r0) = lo | (hi2 << 16);
    }
#pragma unroll
    for (int j = 0; j < 8; ++j) {
      const u32 lo = (u16)vreg[1][j], hi2 = (u16)vreg[3][j];
      *(u32*)(lV + (d0v + 8 + j) * 72 + r0) = lo | (hi2 << 16);
    }
    __syncthreads();

    // ---- prefetch next tile (overlaps compute)
    if (it + 1 < nIter) {
      const int nn = n0 + 64;
#pragma unroll
      for (int i = 0; i < 4; ++i)
        kreg[i] =
            *(const bf16x8*)(Kh + (size_t)(nn + krow + 16 * i) * 128 + kj * 8);
      const u16* vp = Vh + (size_t)(nn + r0) * 128 + d0v;
      vreg[0] = *(const bf16x8*)(vp);
      vreg[1] = *(const bf16x8*)(vp + 8);
      vreg[2] = *(const bf16x8*)(vp + 128);
      vreg[3] = *(const bf16x8*)(vp + 136);
    }

    // ---- S^T = K Q^T (swapped): lane holds S[n][q=c], n via (reg,hi)
    f32x16 s0, s1;
    qkt_block<0>(s0, n0, qlo, hi, c, lK, qf);
    qkt_block<1>(s1, n0, qlo, hi, c, lK, qf);

    // ---- online softmax, fully in-register (reduce over n)
    float mx = -1e30f;
#pragma unroll
    for (int r = 0; r < 16; ++r) mx = fmaxf(mx, fmaxf(s0[r], s1[r]));
    mx = fmaxf(mx, __shfl_xor(mx, 32));
    // T13 defer-rescale: skip the O-rescale while max growth <= 8
    // (P then bounded by e^8 ~ 2981; f32 accO/l_i tolerate).
    if (!__all(mx - m_i <= 8.0f)) {
      const float mn = fmaxf(m_i, mx);
      const float alpha = __expf(m_i - mn);
      m_i = mn;
      l_i *= alpha;
#pragma unroll
      for (int r = 0; r < 16; ++r) {
        const int src = ((r & 3) + 8 * (r >> 2) + 4 * hi) + (lane & 32);
        const float aa = __shfl(alpha, src);
        accO[0][r] *= aa; accO[1][r] *= aa;
        accO[2][r] *= aa; accO[3][r] *= aa;
      }
    }
    float rs = 0.f;
#pragma unroll
    for (int r = 0; r < 16; ++r) {
      const float p0 = __expf(s0[r] - m_i);
      const float p1 = __expf(s1[r] - m_i);
      s0[r] = p0; s1[r] = p1;
      rs += p0 + p1;
    }
    rs += __shfl_xor(rs, 32);
    l_i += rs;

    // ---- O += P V
    pv_block<0>(s0, n0, qlo, hi, c, lV, accO);
    pv_block<1>(s1, n0, qlo, hi, c, lV, accO);
    __syncthreads();
  }

  // ---- epilogue
  const float linv = 1.f / l_i;
#pragma unroll
  for (int r = 0; r < 16; ++r) {
    const int q32 = (r & 3) + 8 * (r >> 2) + 4 * hi;
    const float inv = __shfl(linv, q32 + (lane & 32));
    const int srow = q0 + wave * 32 + q32;
    u16* orow = O + ((size_t)b * 2048 + srow) * 2048 + h * 128 + c;
#pragma unroll
    for (int db = 0; db < 4; ++db) orow[db * 32] = f2b(accO[db][r] * inv);
  }
}

// ---------------------------------------------------------------------------
// Workspace (64 MiB): B0 = xb -> Ob alias, B1=Qb, B2=Kb, B3=Vb.
// wq/wk/wv transposed (25.2 MB) live in d_out (33.5 MB fp32, overwritten by
// gemm_out8 at the end); woT in Kb (dead after attn).
// ---------------------------------------------------------------------------
extern "C" void kernel_launch(void* const* d_in, const int* in_sizes, int n_in,
                              void* d_out, int out_size, void* d_ws, size_t ws_size,
                              hipStream_t stream) {
  const float* x  = (const float*)d_in[0];
  const float* fc = (const float*)d_in[1];
  const float* fs = (const float*)d_in[2];
  const float* wq = (const float*)d_in[3];
  const float* wk = (const float*)d_in[4];
  const float* wv = (const float*)d_in[5];
  const float* wo = (const float*)d_in[6];
  float* out = (float*)d_out;

  u16* ws = (u16*)d_ws;
  const size_t BUF = (size_t)4096 * 2048;
  u16* xb  = ws;
  u16* Ob  = ws;            // reuse B0 (xb dead after gemm_qkv)
  u16* Qb  = ws + 1 * BUF;
  u16* Kb  = ws + 2 * BUF;
  u16* Vb  = ws + 3 * BUF;
  u16* wTall = (u16*)d_out; // 6144*2048 bf16 = 25.2 MB scratch in d_out
  u16* woT = Kb;            // wo transpose (Kb dead after attn)

  hipLaunchKernelGGL(cvt_x, dim3(8192), dim3(256), 0, stream, x, xb);
  hipLaunchKernelGGL(wtrans3, dim3(32, 32, 3), dim3(256), 0, stream, wq, wk, wv, wTall);
  hipLaunchKernelGGL(gemm_qkv, dim3(48, 32), dim3(256), 0, stream, xb, wTall, Qb);
  hipLaunchKernelGGL(rope_kernel, dim3(16384), dim3(256), 0, stream, Qb, Kb, fc, fs);
  hipLaunchKernelGGL(attn4, dim3(512), dim3(256), 0, stream, Qb, Kb, Vb, Ob);
  hipLaunchKernelGGL(wtrans_f32, dim3(32, 32), dim3(256), 0, stream, wo, woT);
  hipLaunchKernelGGL(gemm_out8, dim3(256), dim3(512), 0, stream, Ob, woT, out);
}

// Round 6
// 378.569 us; speedup vs baseline: 1.2357x; 1.0273x over previous
//
#include <hip/hip_runtime.h>

typedef unsigned short u16;
typedef unsigned int u32;
typedef __attribute__((ext_vector_type(8))) short bf16x8;
typedef __attribute__((ext_vector_type(4))) short bf16x4;
typedef __attribute__((ext_vector_type(4))) float f32x4;
typedef __attribute__((ext_vector_type(16))) float f32x16;

#define MFMA(a, b, c) __builtin_amdgcn_mfma_f32_16x16x32_bf16(a, b, c, 0, 0, 0)
#define MFMA32(a, b, c) __builtin_amdgcn_mfma_f32_32x32x16_bf16(a, b, c, 0, 0, 0)
#define ASYNC16(g, l)                                                        \
  __builtin_amdgcn_global_load_lds(                                          \
      (const __attribute__((address_space(1))) u32*)(g),                     \
      (__attribute__((address_space(3))) u32*)(l), 16, 0, 0)

#define SBARRIER()                                                           \
  do {                                                                       \
    asm volatile("" ::: "memory");                                           \
    __builtin_amdgcn_s_barrier();                                            \
    asm volatile("" ::: "memory");                                           \
  } while (0)

__device__ __forceinline__ float b2f(u16 u) {
  union { u32 i; float f; } x; x.i = ((u32)u) << 16; return x.f;
}
__device__ __forceinline__ u16 f2b(float f) {
  union { float f; u32 i; } x; x.f = f;
  return (u16)((x.i + 0x7fff + ((x.i >> 16) & 1)) >> 16);
}
__device__ __forceinline__ f32x4 fzero4() { f32x4 z = {0.f, 0.f, 0.f, 0.f}; return z; }
__device__ __forceinline__ f32x16 fzero16() {
  f32x16 z;
#pragma unroll
  for (int i = 0; i < 16; ++i) z[i] = 0.f;
  return z;
}
// v_cvt_pk_bf16_f32: dst.lo16 = bf16(lo), dst.hi16 = bf16(hi)
__device__ __forceinline__ u32 pkbf16(float lo, float hi) {
  u32 r;
  asm("v_cvt_pk_bf16_f32 %0, %1, %2" : "=v"(r) : "v"(lo), "v"(hi));
  return r;
}

// ---------------------------------------------------------------------------
// x fp32 [4096*2048] -> bf16
// ---------------------------------------------------------------------------
__global__ __launch_bounds__(256) void cvt_x(const float* __restrict__ src,
                                             u16* __restrict__ dst) {
  const int i = (blockIdx.x * 256 + threadIdx.x) * 4;
  const f32x4 v = *(const f32x4*)(src + i);
  bf16x4 o;
  o[0] = (short)f2b(v[0]); o[1] = (short)f2b(v[1]);
  o[2] = (short)f2b(v[2]); o[3] = (short)f2b(v[3]);
  *(bf16x4*)(dst + i) = o;
}

// ---------------------------------------------------------------------------
// Weight transpose + cast (single): W fp32 [K][N] -> WT bf16 [N][K].
// ---------------------------------------------------------------------------
__global__ __launch_bounds__(256) void wtrans_f32(const float* __restrict__ src,
                                                  u16* __restrict__ dst) {
  __shared__ u16 tile[64][65];
  const int k0 = blockIdx.y * 64, n0 = blockIdx.x * 64;
  const int t = threadIdx.x;
  const int tr = t >> 3, tc = t & 7;

#pragma unroll
  for (int hh = 0; hh < 2; ++hh) {
    const int k = tr + hh * 32;
    const float* p = src + (size_t)(k0 + k) * 2048 + n0 + tc * 8;
    const f32x4 a = *(const f32x4*)(p);
    const f32x4 b = *(const f32x4*)(p + 4);
#pragma unroll
    for (int j = 0; j < 4; ++j) tile[k][tc * 8 + j] = f2b(a[j]);
#pragma unroll
    for (int j = 0; j < 4; ++j) tile[k][tc * 8 + 4 + j] = f2b(b[j]);
  }
  __syncthreads();
#pragma unroll
  for (int hh = 0; hh < 2; ++hh) {
    const int n = tr + hh * 32;
    bf16x8 v;
#pragma unroll
    for (int j = 0; j < 8; ++j) v[j] = (short)tile[tc * 8 + j][n];
    *(bf16x8*)(dst + (size_t)(n0 + n) * 2048 + k0 + tc * 8) = v;
  }
}

// z-indexed variant: z=0,1,2 -> wq,wk,wv into wTall + z*2048*2048.
__global__ __launch_bounds__(256) void wtrans3(const float* __restrict__ wq,
                                               const float* __restrict__ wk,
                                               const float* __restrict__ wv,
                                               u16* __restrict__ wTall) {
  __shared__ u16 tile[64][65];
  const int z = blockIdx.z;
  const float* src = (z == 0) ? wq : (z == 1) ? wk : wv;
  u16* dst = wTall + (size_t)z * 2048 * 2048;
  const int k0 = blockIdx.y * 64, n0 = blockIdx.x * 64;
  const int t = threadIdx.x;
  const int tr = t >> 3, tc = t & 7;

#pragma unroll
  for (int hh = 0; hh < 2; ++hh) {
    const int k = tr + hh * 32;
    const float* p = src + (size_t)(k0 + k) * 2048 + n0 + tc * 8;
    const f32x4 a = *(const f32x4*)(p);
    const f32x4 b = *(const f32x4*)(p + 4);
#pragma unroll
    for (int j = 0; j < 4; ++j) tile[k][tc * 8 + j] = f2b(a[j]);
#pragma unroll
    for (int j = 0; j < 4; ++j) tile[k][tc * 8 + 4 + j] = f2b(b[j]);
  }
  __syncthreads();
#pragma unroll
  for (int hh = 0; hh < 2; ++hh) {
    const int n = tr + hh * 32;
    bf16x8 v;
#pragma unroll
    for (int j = 0; j < 8; ++j) v[j] = (short)tile[tc * 8 + j][n];
    *(bf16x8*)(dst + (size_t)(n0 + n) * 2048 + k0 + tc * 8) = v;
  }
}

// ---------------------------------------------------------------------------
// gemm_qkv8: x[4096,2048] @ wTall[6144,2048]^T -> Q/K/V, ring-3 deep pipeline
// (same structure as gemm_out8, proven passing in round 5).
// BM=256, BN=128, BK=64, 512 thr (8 waves 2Mx4N, per-wave 128x32).
// Grid 768 = 16 m-tiles x 48 n-tiles = exactly 3 full rounds at 1 block/CU.
// RING-3 LDS slots (48 KiB each): tile t+2 stages into tile t-1's dead slot;
// counted vmcnt(6) only at tile boundaries (never 0 in-loop).
// XOR chunk swizzle both-sides (rule 21): inverse-swizzled global source +
// linear LDS dest (global_load_lds), swizzled ds_read.
// MFMA order identical to the m97 kernel (64 ascending K=32 steps per acc).
// ---------------------------------------------------------------------------
__global__ __launch_bounds__(512, 2) void gemm_qkv8(const u16* __restrict__ x,
                                                    const u16* __restrict__ wT,
                                                    u16* __restrict__ qkv) {
  __shared__ u16 lds[3 * 24576];  // slot: A[256][64] (16384 u16) + B[128][64] (8192)

  const int orig = blockIdx.x;  // 768 = 8 * 96 -> bijective XCD swizzle
  const int wg = (orig & 7) * 96 + (orig >> 3);
  const int m0 = (wg & 15) * 256;
  const int n0 = (wg >> 4) * 128;

  const int tid = threadIdx.x;
  const int lane = tid & 63;
  const int wave = tid >> 6;
  const int quad = lane >> 4, l16 = lane & 15;
  const int wr = wave >> 2, wc = wave & 3;  // 2 x 4 wave grid

  // staging: inverse-swizzled global column chunk (c ^ row&7), linear LDS dest
  const int r0s = tid >> 3;                // 0..63
  const int c0s = (tid & 7) ^ (r0s & 7);
  const int r1s = r0s + 64;                // 64..127
  const int c1s = (tid & 7) ^ (r1s & 7);

  const u16* gA = x + (size_t)m0 * 2048;
  const u16* gB = wT + (size_t)n0 * 2048;

#define SLOT8(t) (lds + ((t) % 3) * 24576)
#define STAGE_A8(t)                                                          \
  do {                                                                       \
    u16* Lb0 = SLOT8(t) + wave * 512;                                        \
    const u16* g0 = gA + (t) * 64;                                           \
    ASYNC16(g0 + (size_t)r0s * 2048 + c0s * 8, Lb0);                         \
    ASYNC16(g0 + (size_t)r1s * 2048 + c1s * 8, Lb0 + 4096);                  \
    u16* Lb1 = SLOT8(t) + 8192 + wave * 512;                                 \
    const u16* g1 = gA + (size_t)128 * 2048 + (t) * 64;                      \
    ASYNC16(g1 + (size_t)r0s * 2048 + c0s * 8, Lb1);                         \
    ASYNC16(g1 + (size_t)r1s * 2048 + c1s * 8, Lb1 + 4096);                  \
  } while (0)
#define STAGE_B8(t)                                                          \
  do {                                                                       \
    u16* Lb = SLOT8(t) + 16384 + wave * 512;                                 \
    const u16* g = gB + (t) * 64;                                            \
    ASYNC16(g + (size_t)r0s * 2048 + c0s * 8, Lb);                           \
    ASYNC16(g + (size_t)r1s * 2048 + c1s * 8, Lb + 4096);                    \
  } while (0)

  f32x4 acc[8][2];
#pragma unroll
  for (int i = 0; i < 8; ++i) { acc[i][0] = fzero4(); acc[i][1] = fzero4(); }

  // fragment read offsets (u16), swizzle on the k-chunk
  int aoff[8], boff[2];
#pragma unroll
  for (int mb = 0; mb < 8; ++mb) aoff[mb] = (wr * 128 + mb * 16 + l16) * 64;
#pragma unroll
  for (int nb = 0; nb < 2; ++nb) boff[nb] = 16384 + (wc * 32 + nb * 16 + l16) * 64;
  const int ach0 = ((0 * 4 + quad) ^ (l16 & 7)) * 8;  // kstep 0 chunk
  const int ach1 = ((1 * 4 + quad) ^ (l16 & 7)) * 8;  // kstep 1 chunk

  // prologue: stage tiles 0,1 (12 loads/thread), wait tile 0 (6 in flight)
  STAGE_A8(0); STAGE_B8(0);
  STAGE_A8(1); STAGE_B8(1);
  asm volatile("s_waitcnt vmcnt(6)" ::: "memory");
  SBARRIER();

  for (int t = 0; t < 32; ++t) {
    const u16* sl = SLOT8(t);
    bf16x8 af[8], bfr[2];

    // -------- phase A: kstep 0 (16 MFMA) --------
#pragma unroll
    for (int mb = 0; mb < 8; ++mb)
      af[mb] = *(const bf16x8*)(sl + aoff[mb] + ach0);
#pragma unroll
    for (int nb = 0; nb < 2; ++nb)
      bfr[nb] = *(const bf16x8*)(sl + boff[nb] + ach0);
    if (t < 30) STAGE_A8(t + 2);
    SBARRIER();
    asm volatile("s_waitcnt lgkmcnt(0)" ::: "memory");
    __builtin_amdgcn_s_setprio(1);
#pragma unroll
    for (int mb = 0; mb < 8; ++mb)
#pragma unroll
      for (int nb = 0; nb < 2; ++nb)
        acc[mb][nb] = MFMA(af[mb], bfr[nb], acc[mb][nb]);
    __builtin_amdgcn_s_setprio(0);
    SBARRIER();

    // -------- phase B: kstep 1 (16 MFMA) --------
#pragma unroll
    for (int mb = 0; mb < 8; ++mb)
      af[mb] = *(const bf16x8*)(sl + aoff[mb] + ach1);
#pragma unroll
    for (int nb = 0; nb < 2; ++nb)
      bfr[nb] = *(const bf16x8*)(sl + boff[nb] + ach1);
    if (t < 30) STAGE_B8(t + 2);
    SBARRIER();
    asm volatile("s_waitcnt lgkmcnt(0)" ::: "memory");
    __builtin_amdgcn_s_setprio(1);
#pragma unroll
    for (int mb = 0; mb < 8; ++mb)
#pragma unroll
      for (int nb = 0; nb < 2; ++nb)
        acc[mb][nb] = MFMA(af[mb], bfr[nb], acc[mb][nb]);
    __builtin_amdgcn_s_setprio(0);
    // per-K-tile counted wait: t+1 resident, t+2's 6 loads stay in flight
    if (t <= 29) {
      asm volatile("s_waitcnt vmcnt(6)" ::: "memory");
    } else if (t == 30) {
      asm volatile("s_waitcnt vmcnt(0)" ::: "memory");
    }
    SBARRIER();
  }
#undef SLOT8
#undef STAGE_A8
#undef STAGE_B8

  // epilogue: scatter to Q/K/V layout [which][b*16+h][s][d]
  const size_t BUF = (size_t)4096 * 2048;
#pragma unroll
  for (int mb = 0; mb < 8; ++mb)
#pragma unroll
    for (int nb = 0; nb < 2; ++nb)
#pragma unroll
      for (int r = 0; r < 4; ++r) {
        const int row = m0 + wr * 128 + mb * 16 + quad * 4 + r;  // 0..4095
        const int col = n0 + wc * 32 + nb * 16 + l16;            // 0..6143
        const int b = row >> 11, s = row & 2047;
        const int which = col >> 11, rem = col & 2047;
        const int hh = rem >> 7, d = rem & 127;
        const size_t idx = (size_t)which * BUF +
                           (((size_t)(b * 16 + hh) * 2048 + s) * 128 + d);
        qkv[idx] = f2b(acc[mb][nb][r]);
      }
}

// ---------------------------------------------------------------------------
// gemm_out8: O[4096,2048] @ woT^T -> out fp32 (ring-3 pipeline, round-5 form).
// ---------------------------------------------------------------------------
__global__ __launch_bounds__(512, 2) void gemm_out8(const u16* __restrict__ Oin,
                                                    const u16* __restrict__ woT,
                                                    float* __restrict__ out) {
  __shared__ u16 lds[3 * 24576];

  const int orig = blockIdx.x;  // 256 blocks
  const int wg = (orig & 7) * 32 + (orig >> 3);
  const int m0 = (wg >> 4) * 256;
  const int n0 = (wg & 15) * 128;

  const int tid = threadIdx.x;
  const int lane = tid & 63;
  const int wave = tid >> 6;
  const int quad = lane >> 4, l16 = lane & 15;
  const int wr = wave >> 2, wc = wave & 3;

  const int r0s = tid >> 3;
  const int c0s = (tid & 7) ^ (r0s & 7);
  const int r1s = r0s + 64;
  const int c1s = (tid & 7) ^ (r1s & 7);

  const u16* gA = Oin + (size_t)m0 * 2048;
  const u16* gB = woT + (size_t)n0 * 2048;

#define SLOT8(t) (lds + ((t) % 3) * 24576)
#define STAGE_A8(t)                                                          \
  do {                                                                       \
    u16* Lb0 = SLOT8(t) + wave * 512;                                        \
    const u16* g0 = gA + (t) * 64;                                           \
    ASYNC16(g0 + (size_t)r0s * 2048 + c0s * 8, Lb0);                         \
    ASYNC16(g0 + (size_t)r1s * 2048 + c1s * 8, Lb0 + 4096);                  \
    u16* Lb1 = SLOT8(t) + 8192 + wave * 512;                                 \
    const u16* g1 = gA + (size_t)128 * 2048 + (t) * 64;                      \
    ASYNC16(g1 + (size_t)r0s * 2048 + c0s * 8, Lb1);                         \
    ASYNC16(g1 + (size_t)r1s * 2048 + c1s * 8, Lb1 + 4096);                  \
  } while (0)
#define STAGE_B8(t)                                                          \
  do {                                                                       \
    u16* Lb = SLOT8(t) + 16384 + wave * 512;                                 \
    const u16* g = gB + (t) * 64;                                            \
    ASYNC16(g + (size_t)r0s * 2048 + c0s * 8, Lb);                           \
    ASYNC16(g + (size_t)r1s * 2048 + c1s * 8, Lb + 4096);                    \
  } while (0)

  f32x4 acc[8][2];
#pragma unroll
  for (int i = 0; i < 8; ++i) { acc[i][0] = fzero4(); acc[i][1] = fzero4(); }

  int aoff[8], boff[2];
#pragma unroll
  for (int mb = 0; mb < 8; ++mb) aoff[mb] = (wr * 128 + mb * 16 + l16) * 64;
#pragma unroll
  for (int nb = 0; nb < 2; ++nb) boff[nb] = 16384 + (wc * 32 + nb * 16 + l16) * 64;
  const int ach0 = ((0 * 4 + quad) ^ (l16 & 7)) * 8;
  const int ach1 = ((1 * 4 + quad) ^ (l16 & 7)) * 8;

  STAGE_A8(0); STAGE_B8(0);
  STAGE_A8(1); STAGE_B8(1);
  asm volatile("s_waitcnt vmcnt(6)" ::: "memory");
  SBARRIER();

  for (int t = 0; t < 32; ++t) {
    const u16* sl = SLOT8(t);
    bf16x8 af[8], bfr[2];

#pragma unroll
    for (int mb = 0; mb < 8; ++mb)
      af[mb] = *(const bf16x8*)(sl + aoff[mb] + ach0);
#pragma unroll
    for (int nb = 0; nb < 2; ++nb)
      bfr[nb] = *(const bf16x8*)(sl + boff[nb] + ach0);
    if (t < 30) STAGE_A8(t + 2);
    SBARRIER();
    asm volatile("s_waitcnt lgkmcnt(0)" ::: "memory");
    __builtin_amdgcn_s_setprio(1);
#pragma unroll
    for (int mb = 0; mb < 8; ++mb)
#pragma unroll
      for (int nb = 0; nb < 2; ++nb)
        acc[mb][nb] = MFMA(af[mb], bfr[nb], acc[mb][nb]);
    __builtin_amdgcn_s_setprio(0);
    SBARRIER();

#pragma unroll
    for (int mb = 0; mb < 8; ++mb)
      af[mb] = *(const bf16x8*)(sl + aoff[mb] + ach1);
#pragma unroll
    for (int nb = 0; nb < 2; ++nb)
      bfr[nb] = *(const bf16x8*)(sl + boff[nb] + ach1);
    if (t < 30) STAGE_B8(t + 2);
    SBARRIER();
    asm volatile("s_waitcnt lgkmcnt(0)" ::: "memory");
    __builtin_amdgcn_s_setprio(1);
#pragma unroll
    for (int mb = 0; mb < 8; ++mb)
#pragma unroll
      for (int nb = 0; nb < 2; ++nb)
        acc[mb][nb] = MFMA(af[mb], bfr[nb], acc[mb][nb]);
    __builtin_amdgcn_s_setprio(0);
    if (t <= 29) {
      asm volatile("s_waitcnt vmcnt(6)" ::: "memory");
    } else if (t == 30) {
      asm volatile("s_waitcnt vmcnt(0)" ::: "memory");
    }
    SBARRIER();
  }
#undef SLOT8
#undef STAGE_A8
#undef STAGE_B8

#pragma unroll
  for (int mb = 0; mb < 8; ++mb)
#pragma unroll
    for (int nb = 0; nb < 2; ++nb)
#pragma unroll
      for (int r = 0; r < 4; ++r) {
        const int row = m0 + wr * 128 + mb * 16 + quad * 4 + r;
        const int col = n0 + wc * 32 + nb * 16 + l16;
        out[(size_t)row * 2048 + col] = acc[mb][nb][r];
      }
}

// ---------------------------------------------------------------------------
// RoPE in place on Q and K; folds 1/sqrt(128) into Q.
// ---------------------------------------------------------------------------
__global__ __launch_bounds__(256) void rope_kernel(u16* __restrict__ Q,
                                                   u16* __restrict__ K,
                                                   const float* __restrict__ fcos,
                                                   const float* __restrict__ fsin) {
  const int i = blockIdx.x * 256 + threadIdx.x;
  const int d = i & 63;
  const int s = (i >> 6) & 2047;
  const int bh = i >> 17;
  const size_t base = ((size_t)bh * 2048 + s) * 128;
  const float c = fcos[s * 64 + d];
  const float sn = fsin[s * 64 + d];
  const float qs = 0.08838834764831845f;

  const float q0 = b2f(Q[base + d]), q1 = b2f(Q[base + d + 64]);
  Q[base + d] = f2b((q0 * c - q1 * sn) * qs);
  Q[base + d + 64] = f2b((q1 * c + q0 * sn) * qs);
  const float k0 = b2f(K[base + d]), k1 = b2f(K[base + d + 64]);
  K[base + d] = f2b(k0 * c - k1 * sn);
  K[base + d + 64] = f2b(k1 * c + k0 * sn);
}

// ---------------------------------------------------------------------------
// Flash attention v4 (round-5 form: T13 defer-rescale + T5 setprio).
// ---------------------------------------------------------------------------
// S^T C-layout (32x32): col = lane&31 = q, row(reg,hi) = (r&3)+8*(r>>2)+4*hi.
template <int NB>
__device__ __forceinline__ void qkt_block(f32x16& sv, int n0, int qlo, int hi,
                                          int c, const u16* lK,
                                          const bf16x8* qf) {
  const int lo = n0 + NB * 32;
  if (lo < qlo + 32) {
    sv = fzero16();
    __builtin_amdgcn_s_setprio(1);
#pragma unroll
    for (int kc = 0; kc < 8; ++kc) {
      const bf16x8 kf =
          *(const bf16x8*)(lK + (NB * 32 + c) * 136 + kc * 16 + hi * 8);
      sv = MFMA32(kf, qf[kc], sv);
    }
    __builtin_amdgcn_s_setprio(0);
    if (lo == qlo) {  // diagonal 32x32: mask n32 > q32
#pragma unroll
      for (int r = 0; r < 16; ++r) {
        const int n32 = (r & 3) + 8 * (r >> 2) + 4 * hi;
        if (n32 > c) sv[r] = -1e30f;
      }
    }
  } else {
#pragma unroll
    for (int r = 0; r < 16; ++r) sv[r] = -1e30f;
  }
}

template <int NB>
__device__ __forceinline__ void pv_block(const f32x16& sv, int n0, int qlo,
                                         int hi, int c, const u16* lV,
                                         f32x16* accO) {
  if (n0 + NB * 32 < qlo + 32) {
#pragma unroll
    for (int half = 0; half < 2; ++half) {
      const int rb = half * 8;
      const u32 pA = pkbf16(sv[rb + 0], sv[rb + 1]);
      const u32 pB = pkbf16(sv[rb + 2], sv[rb + 3]);
      const u32 pC = pkbf16(sv[rb + 4], sv[rb + 5]);
      const u32 pD = pkbf16(sv[rb + 6], sv[rb + 7]);
      const u32 xA = (u32)__shfl_xor((int)pA, 32);
      const u32 xB = (u32)__shfl_xor((int)pB, 32);
      const u32 xC = (u32)__shfl_xor((int)pC, 32);
      const u32 xD = (u32)__shfl_xor((int)pD, 32);
      bf16x8 pa;
      u32* pw = (u32*)&pa;
      pw[0] = hi ? xC : pA;
      pw[1] = hi ? xD : pB;
      pw[2] = hi ? pC : xA;
      pw[3] = hi ? pD : xB;
      __builtin_amdgcn_s_setprio(1);
#pragma unroll
      for (int db = 0; db < 4; ++db) {
        const bf16x8 vf = *(const bf16x8*)(lV + (db * 32 + c) * 72 +
                                           NB * 32 + half * 16 + hi * 8);
        accO[db] = MFMA32(pa, vf, accO[db]);
      }
      __builtin_amdgcn_s_setprio(0);
    }
  }
}

__global__ __launch_bounds__(256, 2) void attn4(const u16* __restrict__ Q,
                                                const u16* __restrict__ K,
                                                const u16* __restrict__ V,
                                                u16* __restrict__ O) {
  __shared__ u16 lK[64 * 136];   // K-tile [n][d], stride 272B (odd x16B)
  __shared__ u16 lV[128 * 72];   // V^T    [d][n], stride 144B (odd x16B)

  const int bid = blockIdx.x;
  const int bh = (bid & 7) + 8 * ((bid >> 3) & 3);  // head-group per XCD
  const int tq = bid >> 5;
  const int qt = (tq < 8) ? tq : 23 - tq;           // pair: per-CU 34 iters
  const int q0 = qt * 128;
  const int b = bh >> 4, h = bh & 15;
  const u16* Qh = Q + (size_t)bh * 2048 * 128;
  const u16* Kh = K + (size_t)bh * 2048 * 128;
  const u16* Vh = V + (size_t)bh * 2048 * 128;

  const int tid = threadIdx.x;
  const int lane = tid & 63, wave = tid >> 6;
  const int hi = lane >> 5, c = lane & 31;
  const int qlo = q0 + wave * 32;
  const int krow = tid >> 4, kj = tid & 15;
  const int r0 = (tid & 31) * 2, d0v = (tid >> 5) * 16;

  // Q fragments (B-operand): lane holds Q[q0+wave*32+c][kc*16 + hi*8 + j]
  bf16x8 qf[8];
  {
    const u16* qrow = Qh + (size_t)(q0 + wave * 32 + c) * 128 + hi * 8;
#pragma unroll
    for (int kc = 0; kc < 8; ++kc) qf[kc] = *(const bf16x8*)(qrow + kc * 16);
  }

  float m_i = -1e30f, l_i = 0.f;
  f32x16 accO[4];
#pragma unroll
  for (int db = 0; db < 4; ++db) accO[db] = fzero16();

  const int nIter = 2 * qt + 2;

  bf16x8 kreg[4], vreg[4];
  {
#pragma unroll
    for (int i = 0; i < 4; ++i)
      kreg[i] = *(const bf16x8*)(Kh + (size_t)(krow + 16 * i) * 128 + kj * 8);
    const u16* vp = Vh + (size_t)r0 * 128 + d0v;
    vreg[0] = *(const bf16x8*)(vp);
    vreg[1] = *(const bf16x8*)(vp + 8);
    vreg[2] = *(const bf16x8*)(vp + 128);
    vreg[3] = *(const bf16x8*)(vp + 136);
  }

  for (int it = 0; it < nIter; ++it) {
    const int n0 = it * 64;
#pragma unroll
    for (int i = 0; i < 4; ++i)
      *(bf16x8*)(lK + (krow + 16 * i) * 136 + kj * 8) = kreg[i];
#pragma unroll
    for (int j = 0; j < 8; ++j) {
      const u32 lo = (u16)vreg[0][j], hi2 = (u16)vreg[2][j];
      *(u32*)(lV + (d0v + j) * 72 + r0) = lo | (hi2 << 16);
    }
#pragma unroll
    for (int j = 0; j < 8; ++j) {
      const u32 lo = (u16)vreg[1][j], hi2 = (u16)vreg[3][j];
      *(u32*)(lV + (d0v + 8 + j) * 72 + r0) = lo | (hi2 << 16);
    }
    __syncthreads();

    if (it + 1 < nIter) {
      const int nn = n0 + 64;
#pragma unroll
      for (int i = 0; i < 4; ++i)
        kreg[i] =
            *(const bf16x8*)(Kh + (size_t)(nn + krow + 16 * i) * 128 + kj * 8);
      const u16* vp = Vh + (size_t)(nn + r0) * 128 + d0v;
      vreg[0] = *(const bf16x8*)(vp);
      vreg[1] = *(const bf16x8*)(vp + 8);
      vreg[2] = *(const bf16x8*)(vp + 128);
      vreg[3] = *(const bf16x8*)(vp + 136);
    }

    f32x16 s0, s1;
    qkt_block<0>(s0, n0, qlo, hi, c, lK, qf);
    qkt_block<1>(s1, n0, qlo, hi, c, lK, qf);

    float mx = -1e30f;
#pragma unroll
    for (int r = 0; r < 16; ++r) mx = fmaxf(mx, fmaxf(s0[r], s1[r]));
    mx = fmaxf(mx, __shfl_xor(mx, 32));
    // T13 defer-rescale: skip O-rescale while max growth <= 8
    if (!__all(mx - m_i <= 8.0f)) {
      const float mn = fmaxf(m_i, mx);
      const float alpha = __expf(m_i - mn);
      m_i = mn;
      l_i *= alpha;
#pragma unroll
      for (int r = 0; r < 16; ++r) {
        const int src = ((r & 3) + 8 * (r >> 2) + 4 * hi) + (lane & 32);
        const float aa = __shfl(alpha, src);
        accO[0][r] *= aa; accO[1][r] *= aa;
        accO[2][r] *= aa; accO[3][r] *= aa;
      }
    }
    float rs = 0.f;
#pragma unroll
    for (int r = 0; r < 16; ++r) {
      const float p0 = __expf(s0[r] - m_i);
      const float p1 = __expf(s1[r] - m_i);
      s0[r] = p0; s1[r] = p1;
      rs += p0 + p1;
    }
    rs += __shfl_xor(rs, 32);
    l_i += rs;

    pv_block<0>(s0, n0, qlo, hi, c, lV, accO);
    pv_block<1>(s1, n0, qlo, hi, c, lV, accO);
    __syncthreads();
  }

  const float linv = 1.f / l_i;
#pragma unroll
  for (int r = 0; r < 16; ++r) {
    const int q32 = (r & 3) + 8 * (r >> 2) + 4 * hi;
    const float inv = __shfl(linv, q32 + (lane & 32));
    const int srow = q0 + wave * 32 + q32;
    u16* orow = O + ((size_t)b * 2048 + srow) * 2048 + h * 128 + c;
#pragma unroll
    for (int db = 0; db < 4; ++db) orow[db * 32] = f2b(accO[db][r] * inv);
  }
}

// ---------------------------------------------------------------------------
// Workspace (64 MiB): B0 = xb -> Ob alias, B1=Qb, B2=Kb, B3=Vb.
// wq/wk/wv transposed (25.2 MB) live in d_out (33.5 MB fp32, overwritten by
// gemm_out8 at the end); woT in Kb (dead after attn).
// ---------------------------------------------------------------------------
extern "C" void kernel_launch(void* const* d_in, const int* in_sizes, int n_in,
                              void* d_out, int out_size, void* d_ws, size_t ws_size,
                              hipStream_t stream) {
  const float* x  = (const float*)d_in[0];
  const float* fc = (const float*)d_in[1];
  const float* fs = (const float*)d_in[2];
  const float* wq = (const float*)d_in[3];
  const float* wk = (const float*)d_in[4];
  const float* wv = (const float*)d_in[5];
  const float* wo = (const float*)d_in[6];
  float* out = (float*)d_out;

  u16* ws = (u16*)d_ws;
  const size_t BUF = (size_t)4096 * 2048;
  u16* xb  = ws;
  u16* Ob  = ws;            // reuse B0 (xb dead after gemm_qkv8)
  u16* Qb  = ws + 1 * BUF;
  u16* Kb  = ws + 2 * BUF;
  u16* Vb  = ws + 3 * BUF;
  u16* wTall = (u16*)d_out; // 6144*2048 bf16 = 25.2 MB scratch in d_out
  u16* woT = Kb;            // wo transpose (Kb dead after attn)

  hipLaunchKernelGGL(cvt_x, dim3(8192), dim3(256), 0, stream, x, xb);
  hipLaunchKernelGGL(wtrans3, dim3(32, 32, 3), dim3(256), 0, stream, wq, wk, wv, wTall);
  hipLaunchKernelGGL(gemm_qkv8, dim3(768), dim3(512), 0, stream, xb, wTall, Qb);
  hipLaunchKernelGGL(rope_kernel, dim3(16384), dim3(256), 0, stream, Qb, Kb, fc, fs);
  hipLaunchKernelGGL(attn4, dim3(512), dim3(256), 0, stream, Qb, Kb, Vb, Ob);
  hipLaunchKernelGGL(wtrans_f32, dim3(32, 32), dim3(256), 0, stream, wo, woT);
  hipLaunchKernelGGL(gemm_out8, dim3(256), dim3(512), 0, stream, Ob, woT, out);
}